// Round 3
// baseline (1561.018 us; speedup 1.0000x reference)
//
#include <hip/hip_runtime.h>
#include <math.h>

// ---------------- problem constants ----------------
#define T_LEN   1024
#define HIDDEN  2048
#define NUMV    16
#define NUMK    8
#define HKD     128
#define QKVZ_N  6144   // 2*KEY_DIM + 2*VALUE_DIM
#define KEY_DIM 1024
#define VAL_DIM 2048

__device__ __forceinline__ float sigmoidf_(float x) { return 1.f / (1.f + expf(-x)); }

// ---------------------------------------------------------------------------
// GEMM: C[M,N] = A[M,K] * B[N,K]^T   (both row-major, K contiguous)
// 64x64 tile, K-tile 16, 4x4 per thread, fp32.
// ---------------------------------------------------------------------------
__global__ __launch_bounds__(256) void gemm_bt(const float* __restrict__ A,
                                               const float* __restrict__ B,
                                               float* __restrict__ C,
                                               int M, int N, int K) {
    __shared__ float As[16][68];
    __shared__ float Bs[16][68];
    const int tid = threadIdx.x;
    const int m0 = blockIdx.y * 64;
    const int n0 = blockIdx.x * 64;
    const int tx = tid & 15;        // n micro
    const int ty = tid >> 4;        // m micro
    const int lr = tid >> 2;        // 0..63 tile row for staging
    const int lk = (tid & 3) << 2;  // 0,4,8,12 k offset for staging

    float acc[4][4];
#pragma unroll
    for (int i = 0; i < 4; ++i)
#pragma unroll
        for (int j = 0; j < 4; ++j) acc[i][j] = 0.f;

    for (int k0 = 0; k0 < K; k0 += 16) {
        float4 av = *(const float4*)(A + (size_t)(m0 + lr) * K + k0 + lk);
        float4 bv = make_float4(0.f, 0.f, 0.f, 0.f);
        if (n0 + lr < N) bv = *(const float4*)(B + (size_t)(n0 + lr) * K + k0 + lk);
        __syncthreads();
        As[lk + 0][lr] = av.x; As[lk + 1][lr] = av.y; As[lk + 2][lr] = av.z; As[lk + 3][lr] = av.w;
        Bs[lk + 0][lr] = bv.x; Bs[lk + 1][lr] = bv.y; Bs[lk + 2][lr] = bv.z; Bs[lk + 3][lr] = bv.w;
        __syncthreads();
#pragma unroll
        for (int kk = 0; kk < 16; ++kk) {
            float4 a4 = *(const float4*)&As[kk][ty << 2];
            float4 b4 = *(const float4*)&Bs[kk][tx << 2];
            const float ar[4] = {a4.x, a4.y, a4.z, a4.w};
            const float br[4] = {b4.x, b4.y, b4.z, b4.w};
#pragma unroll
            for (int i = 0; i < 4; ++i)
#pragma unroll
                for (int j = 0; j < 4; ++j) acc[i][j] = fmaf(ar[i], br[j], acc[i][j]);
        }
    }
#pragma unroll
    for (int i = 0; i < 4; ++i) {
        const int row = m0 + (ty << 2) + i;
        const int col = n0 + (tx << 2);
        if (col + 3 < N) {
            *(float4*)(C + (size_t)row * N + col) =
                make_float4(acc[i][0], acc[i][1], acc[i][2], acc[i][3]);
        } else {
#pragma unroll
            for (int j = 0; j < 4; ++j)
                if (col + j < N) C[(size_t)row * N + col + j] = acc[i][j];
        }
    }
}

// ---------------------------------------------------------------------------
// Depthwise causal conv1d (K=4) + SiLU over mixed [q|k|v] channel layout.
// qkvz row layout per k-head block of 768: [q 128 | k 128 | v 256 | z 256]
// ---------------------------------------------------------------------------
__global__ __launch_bounds__(256) void conv_silu(const float* __restrict__ qkvz,
                                                 const float* __restrict__ conv_w,
                                                 float* __restrict__ qc,
                                                 float* __restrict__ kc,
                                                 float* __restrict__ vc) {
    const int idx = blockIdx.x * 256 + threadIdx.x;  // T_LEN*4096 threads
    const int t = idx >> 12;
    const int c = idx & 4095;
    int col;
    float* dst;
    if (c < 1024) {            // q
        col = ((c >> 7) * 768) + (c & 127);
        dst = qc + t * 1024 + c;
    } else if (c < 2048) {     // k
        const int cc = c - 1024;
        col = ((cc >> 7) * 768) + 128 + (cc & 127);
        dst = kc + t * 1024 + cc;
    } else {                   // v
        const int cc = c - 2048;
        col = ((cc >> 8) * 768) + 256 + (cc & 255);
        dst = vc + t * 2048 + cc;
    }
    const float w0 = conv_w[c * 4 + 0];
    const float w1 = conv_w[c * 4 + 1];
    const float w2 = conv_w[c * 4 + 2];
    const float w3 = conv_w[c * 4 + 3];
    float acc = qkvz[(size_t)t * QKVZ_N + col] * w3;
    if (t >= 1) acc = fmaf(qkvz[(size_t)(t - 1) * QKVZ_N + col], w2, acc);
    if (t >= 2) acc = fmaf(qkvz[(size_t)(t - 2) * QKVZ_N + col], w1, acc);
    if (t >= 3) acc = fmaf(qkvz[(size_t)(t - 3) * QKVZ_N + col], w0, acc);
    *dst = acc * sigmoidf_(acc);  // silu
}

// ---------------------------------------------------------------------------
// L2 normalize q and k per (t, k-head); fold scale=HK^-0.5 into q.
// ---------------------------------------------------------------------------
__global__ __launch_bounds__(64) void l2norm_qk(float* __restrict__ qc, float* __restrict__ kc) {
    const int b = blockIdx.x;
    const int t = b >> 4;
    const int hh = b & 15;
    float* p;
    float extra;
    if (hh < 8) { p = qc + t * 1024 + hh * 128; extra = 0.08838834764831845f; }  // 128^-0.5
    else        { p = kc + t * 1024 + (hh - 8) * 128; extra = 1.f; }
    const int j = threadIdx.x * 2;
    float2 x = *(const float2*)(p + j);
    float ss = x.x * x.x + x.y * x.y;
#pragma unroll
    for (int m = 1; m < 64; m <<= 1) ss += __shfl_xor(ss, m, 64);
    const float r = rsqrtf(ss + 1e-6f) * extra;
    *(float2*)(p + j) = make_float2(x.x * r, x.y * r);
}

// ---------------------------------------------------------------------------
// Gates: beta = sigmoid(b); decay = exp(-exp(A_log)*softplus(a + dt_bias))
// ---------------------------------------------------------------------------
__global__ __launch_bounds__(256) void gates(const float* __restrict__ ba,
                                             const float* __restrict__ dt_bias,
                                             const float* __restrict__ A_log,
                                             float* __restrict__ dec,
                                             float* __restrict__ bet) {
    const int i = blockIdx.x * 256 + threadIdx.x;  // T_LEN*16
    const int t = i >> 4;
    const int vh = i & 15;
    const int kh = vh >> 1;
    const int r = vh & 1;
    const float b = ba[t * 32 + kh * 4 + r];
    const float a = ba[t * 32 + kh * 4 + 2 + r];
    bet[i] = 1.f / (1.f + expf(-b));
    const float x = a + dt_bias[vh];
    const float sp = (x > 0.f) ? (x + log1pf(expf(-x))) : log1pf(expf(x));
    dec[i] = expf(-expf(A_log[vh]) * sp);
}

// ---------------------------------------------------------------------------
// Gated delta-rule recurrence, v3.
//
// 256 blocks x 64 threads (1 wave/block).
//   block b: head h = b>>4, v-group vg = b&15 (8 v-columns per block)
//   lane l:  kg = l & 7  (LOW bits -> reductions are xor 1/2/4; 1 and 2
//            compile to DPP quad_perm at VALU rate, only 4 is a ds_swizzle),
//            vi = l >> 3 (column within group)
// Each lane holds S[rows kg*16..+16][column vg*8+vi] = 16 regs.
// Loads software-pipelined with a 4-slot ring (distance 4 covers ~900 cyc
// cold-load latency at ~200 cyc/step).  No LDS, no barriers.
// ---------------------------------------------------------------------------
__global__ __launch_bounds__(64) void recur(const float* __restrict__ qc,
                                            const float* __restrict__ kc,
                                            const float* __restrict__ vc,
                                            const float* __restrict__ dec,
                                            const float* __restrict__ bet,
                                            float* __restrict__ o) {
    const int b = blockIdx.x;
    const int h = b >> 4;        // value head 0..15
    const int vg = b & 15;       // v-group 0..15
    const int kh = h >> 1;       // key head
    const int lane = threadIdx.x;
    const int kg = lane & 7;     // k rows kg*16..+16  (low bits!)
    const int vi = lane >> 3;    // column within group
    const int v = vg * 8 + vi;   // 0..127

    const float* kbase = kc + kh * 128 + kg * 16;
    const float* qbase = qc + kh * 128 + kg * 16;
    const float* vbase = vc + h * 128 + v;
    const float* dbase = dec + h;
    const float* bbase = bet + h;
    float* obase = o + h * 128 + v;

    float S[16];
#pragma unroll
    for (int j = 0; j < 16; ++j) S[j] = 0.f;

    float4 K[4][4], Q[4][4];
    float V[4], D[4], Bt[4];

#pragma unroll
    for (int s = 0; s < 4; ++s) {
        const float4* kp = (const float4*)(kbase + (size_t)s * 1024);
        const float4* qp = (const float4*)(qbase + (size_t)s * 1024);
#pragma unroll
        for (int i = 0; i < 4; ++i) { K[s][i] = kp[i]; Q[s][i] = qp[i]; }
        V[s] = vbase[(size_t)s * 2048];
        D[s] = dbase[(size_t)s * 16];
        Bt[s] = bbase[(size_t)s * 16];
    }

#pragma unroll 4
    for (int t = 0; t < T_LEN; ++t) {
        const int s = t & 3;
        // ---- compute step t from slot s ----
        float c0 = 0.f, c1 = 0.f, c2 = 0.f, c3 = 0.f;
#pragma unroll
        for (int i = 0; i < 4; ++i) {
            c0 = fmaf(K[s][i].x, S[4 * i + 0], c0);
            c1 = fmaf(K[s][i].y, S[4 * i + 1], c1);
            c2 = fmaf(K[s][i].z, S[4 * i + 2], c2);
            c3 = fmaf(K[s][i].w, S[4 * i + 3], c3);
        }
        float kv = (c0 + c1) + (c2 + c3);
        kv += __shfl_xor(kv, 1, 64);   // DPP quad_perm
        kv += __shfl_xor(kv, 2, 64);   // DPP quad_perm
        kv += __shfl_xor(kv, 4, 64);   // ds_swizzle (the one LDS-pipe op on chain)
        const float d = D[s], be = Bt[s];
        const float delta = (V[s] - d * kv) * be;
        float o0 = 0.f, o1 = 0.f, o2 = 0.f, o3 = 0.f;
#pragma unroll
        for (int i = 0; i < 4; ++i) {
            S[4 * i + 0] = fmaf(S[4 * i + 0], d, K[s][i].x * delta); o0 = fmaf(Q[s][i].x, S[4 * i + 0], o0);
            S[4 * i + 1] = fmaf(S[4 * i + 1], d, K[s][i].y * delta); o1 = fmaf(Q[s][i].y, S[4 * i + 1], o1);
            S[4 * i + 2] = fmaf(S[4 * i + 2], d, K[s][i].z * delta); o2 = fmaf(Q[s][i].z, S[4 * i + 2], o2);
            S[4 * i + 3] = fmaf(S[4 * i + 3], d, K[s][i].w * delta); o3 = fmaf(Q[s][i].w, S[4 * i + 3], o3);
        }
        float oo = (o0 + o1) + (o2 + o3);
        oo += __shfl_xor(oo, 1, 64);
        oo += __shfl_xor(oo, 2, 64);
        oo += __shfl_xor(oo, 4, 64);
        if (kg == 0) obase[(size_t)t * 2048] = oo;
        // ---- prefetch step t+4 into slot s ----
        const int tn = t + 4;
        if (tn < T_LEN) {
            const float4* kp = (const float4*)(kbase + (size_t)tn * 1024);
            const float4* qp = (const float4*)(qbase + (size_t)tn * 1024);
#pragma unroll
            for (int i = 0; i < 4; ++i) { K[s][i] = kp[i]; Q[s][i] = qp[i]; }
            V[s] = vbase[(size_t)tn * 2048];
            D[s] = dbase[(size_t)tn * 16];
            Bt[s] = bbase[(size_t)tn * 16];
        }
    }
}

// ---------------------------------------------------------------------------
// Gated RMSNorm: xf = o * silu(z); xn = xf * rsqrt(mean(xf^2)+eps) * w
// ---------------------------------------------------------------------------
__global__ __launch_bounds__(64) void gated_norm(const float* __restrict__ o,
                                                 const float* __restrict__ qkvz,
                                                 const float* __restrict__ nw,
                                                 float* __restrict__ xn) {
    const int b = blockIdx.x;
    const int t = b >> 4;
    const int vh = b & 15;
    const int kh = vh >> 1;
    const int r = vh & 1;
    const float* op = o + (size_t)t * 2048 + vh * 128;
    const float* zp = qkvz + (size_t)t * QKVZ_N + kh * 768 + 512 + r * 128;
    const int j = threadIdx.x * 2;
    const float2 ov = *(const float2*)(op + j);
    const float2 zv = *(const float2*)(zp + j);
    const float f0 = ov.x * zv.x / (1.f + expf(-zv.x));
    const float f1 = ov.y * zv.y / (1.f + expf(-zv.y));
    float ss = f0 * f0 + f1 * f1;
#pragma unroll
    for (int m = 1; m < 64; m <<= 1) ss += __shfl_xor(ss, m, 64);
    const float rs = rsqrtf(ss * (1.f / 128.f) + 1e-6f);
    float* xp = xn + (size_t)t * 2048 + vh * 128;
    *(float2*)(xp + j) = make_float2(f0 * rs * nw[j], f1 * rs * nw[j + 1]);
}

// ---------------------------------------------------------------------------
extern "C" void kernel_launch(void* const* d_in, const int* in_sizes, int n_in,
                              void* d_out, int out_size, void* d_ws, size_t ws_size,
                              hipStream_t stream) {
    const float* hidden  = (const float*)d_in[0];
    const float* w_qkvz  = (const float*)d_in[1];
    const float* w_ba    = (const float*)d_in[2];
    const float* conv_w  = (const float*)d_in[3];
    const float* dt_bias = (const float*)d_in[4];
    const float* A_log   = (const float*)d_in[5];
    const float* norm_w  = (const float*)d_in[6];
    const float* w_out   = (const float*)d_in[7];
    float* out = (float*)d_out;

    float* ws   = (float*)d_ws;
    float* qkvz = ws;                  // 1024*6144
    float* ba   = qkvz + 6291456;      // 1024*32
    float* qc   = ba + 32768;          // 1024*1024
    float* kc   = qc + 1048576;        // 1024*1024
    float* vc   = kc + 1048576;        // 1024*2048
    float* dcy  = vc + 2097152;        // 1024*16
    float* bet  = dcy + 16384;         // 1024*16
    float* o    = bet + 16384;         // 1024*2048
    float* xn   = o + 2097152;         // 1024*2048

    gemm_bt<<<dim3(QKVZ_N / 64, T_LEN / 64), 256, 0, stream>>>(hidden, w_qkvz, qkvz,
                                                               T_LEN, QKVZ_N, HIDDEN);
    gemm_bt<<<dim3(1, T_LEN / 64), 256, 0, stream>>>(hidden, w_ba, ba, T_LEN, 32, HIDDEN);
    conv_silu<<<(T_LEN * 4096) / 256, 256, 0, stream>>>(qkvz, conv_w, qc, kc, vc);
    l2norm_qk<<<T_LEN * 16, 64, 0, stream>>>(qc, kc);
    gates<<<(T_LEN * 16) / 256, 256, 0, stream>>>(ba, dt_bias, A_log, dcy, bet);
    recur<<<256, 64, 0, stream>>>(qc, kc, vc, dcy, bet, o);
    gated_norm<<<T_LEN * 16, 64, 0, stream>>>(o, qkvz, norm_w, xn);
    gemm_bt<<<dim3(VAL_DIM / 64, T_LEN / 64), 256, 0, stream>>>(xn, w_out, out,
                                                                T_LEN, VAL_DIM, HIDDEN);
}

// Round 4
// 1057.852 us; speedup vs baseline: 1.4756x; 1.4756x over previous
//
#include <hip/hip_runtime.h>
#include <math.h>

// ---------------- problem constants ----------------
#define T_LEN   1024
#define HIDDEN  2048
#define NUMV    16
#define NUMK    8
#define HKD     128
#define QKVZ_N  6144   // 2*KEY_DIM + 2*VALUE_DIM
#define KEY_DIM 1024
#define VAL_DIM 2048

__device__ __forceinline__ float sigmoidf_(float x) { return 1.f / (1.f + expf(-x)); }

// DPP lane-exchange at VALU rate (row-local, all our exchanges are within 8 lanes)
template <int CTRL>
__device__ __forceinline__ float dpp_mov(float x) {
    return __int_as_float(
        __builtin_amdgcn_update_dpp(0, __float_as_int(x), CTRL, 0xF, 0xF, true));
}
// xor1 = quad_perm(1,0,3,2)=0xB1; xor2 = quad_perm(2,3,0,1)=0x4E;
// "xor4" after xor1+xor2 = row_half_mirror(0x141): every lane of a 4-group holds
// the 4-group sum, and half-mirror always pairs lanes across the two 4-groups.
__device__ __forceinline__ float red8_dpp(float x) {
    x += dpp_mov<0xB1>(x);
    x += dpp_mov<0x4E>(x);
    x += dpp_mov<0x141>(x);
    return x;
}

// ---------------------------------------------------------------------------
// GEMM: C[M,N] = A[M,K] * B[N,K]^T   (both row-major, K contiguous)
// 64x64 tile, K-tile 16, 4x4 per thread, fp32.
// ---------------------------------------------------------------------------
__global__ __launch_bounds__(256) void gemm_bt(const float* __restrict__ A,
                                               const float* __restrict__ B,
                                               float* __restrict__ C,
                                               int M, int N, int K) {
    __shared__ float As[16][68];
    __shared__ float Bs[16][68];
    const int tid = threadIdx.x;
    const int m0 = blockIdx.y * 64;
    const int n0 = blockIdx.x * 64;
    const int tx = tid & 15;        // n micro
    const int ty = tid >> 4;        // m micro
    const int lr = tid >> 2;        // 0..63 tile row for staging
    const int lk = (tid & 3) << 2;  // 0,4,8,12 k offset for staging

    float acc[4][4];
#pragma unroll
    for (int i = 0; i < 4; ++i)
#pragma unroll
        for (int j = 0; j < 4; ++j) acc[i][j] = 0.f;

    for (int k0 = 0; k0 < K; k0 += 16) {
        float4 av = *(const float4*)(A + (size_t)(m0 + lr) * K + k0 + lk);
        float4 bv = make_float4(0.f, 0.f, 0.f, 0.f);
        if (n0 + lr < N) bv = *(const float4*)(B + (size_t)(n0 + lr) * K + k0 + lk);
        __syncthreads();
        As[lk + 0][lr] = av.x; As[lk + 1][lr] = av.y; As[lk + 2][lr] = av.z; As[lk + 3][lr] = av.w;
        Bs[lk + 0][lr] = bv.x; Bs[lk + 1][lr] = bv.y; Bs[lk + 2][lr] = bv.z; Bs[lk + 3][lr] = bv.w;
        __syncthreads();
#pragma unroll
        for (int kk = 0; kk < 16; ++kk) {
            float4 a4 = *(const float4*)&As[kk][ty << 2];
            float4 b4 = *(const float4*)&Bs[kk][tx << 2];
            const float ar[4] = {a4.x, a4.y, a4.z, a4.w};
            const float br[4] = {b4.x, b4.y, b4.z, b4.w};
#pragma unroll
            for (int i = 0; i < 4; ++i)
#pragma unroll
                for (int j = 0; j < 4; ++j) acc[i][j] = fmaf(ar[i], br[j], acc[i][j]);
        }
    }
#pragma unroll
    for (int i = 0; i < 4; ++i) {
        const int row = m0 + (ty << 2) + i;
        const int col = n0 + (tx << 2);
        if (col + 3 < N) {
            *(float4*)(C + (size_t)row * N + col) =
                make_float4(acc[i][0], acc[i][1], acc[i][2], acc[i][3]);
        } else {
#pragma unroll
            for (int j = 0; j < 4; ++j)
                if (col + j < N) C[(size_t)row * N + col + j] = acc[i][j];
        }
    }
}

// ---------------------------------------------------------------------------
// Depthwise causal conv1d (K=4) + SiLU over mixed [q|k|v] channel layout.
// ---------------------------------------------------------------------------
__global__ __launch_bounds__(256) void conv_silu(const float* __restrict__ qkvz,
                                                 const float* __restrict__ conv_w,
                                                 float* __restrict__ qc,
                                                 float* __restrict__ kc,
                                                 float* __restrict__ vc) {
    const int idx = blockIdx.x * 256 + threadIdx.x;  // T_LEN*4096 threads
    const int t = idx >> 12;
    const int c = idx & 4095;
    int col;
    float* dst;
    if (c < 1024) {            // q
        col = ((c >> 7) * 768) + (c & 127);
        dst = qc + t * 1024 + c;
    } else if (c < 2048) {     // k
        const int cc = c - 1024;
        col = ((cc >> 7) * 768) + 128 + (cc & 127);
        dst = kc + t * 1024 + cc;
    } else {                   // v
        const int cc = c - 2048;
        col = ((cc >> 8) * 768) + 256 + (cc & 255);
        dst = vc + t * 2048 + cc;
    }
    const float w0 = conv_w[c * 4 + 0];
    const float w1 = conv_w[c * 4 + 1];
    const float w2 = conv_w[c * 4 + 2];
    const float w3 = conv_w[c * 4 + 3];
    float acc = qkvz[(size_t)t * QKVZ_N + col] * w3;
    if (t >= 1) acc = fmaf(qkvz[(size_t)(t - 1) * QKVZ_N + col], w2, acc);
    if (t >= 2) acc = fmaf(qkvz[(size_t)(t - 2) * QKVZ_N + col], w1, acc);
    if (t >= 3) acc = fmaf(qkvz[(size_t)(t - 3) * QKVZ_N + col], w0, acc);
    *dst = acc * sigmoidf_(acc);  // silu
}

// ---------------------------------------------------------------------------
// L2 normalize q and k per (t, k-head); fold scale=HK^-0.5 into q.
// ---------------------------------------------------------------------------
__global__ __launch_bounds__(64) void l2norm_qk(float* __restrict__ qc, float* __restrict__ kc) {
    const int b = blockIdx.x;
    const int t = b >> 4;
    const int hh = b & 15;
    float* p;
    float extra;
    if (hh < 8) { p = qc + t * 1024 + hh * 128; extra = 0.08838834764831845f; }  // 128^-0.5
    else        { p = kc + t * 1024 + (hh - 8) * 128; extra = 1.f; }
    const int j = threadIdx.x * 2;
    float2 x = *(const float2*)(p + j);
    float ss = x.x * x.x + x.y * x.y;
#pragma unroll
    for (int m = 1; m < 64; m <<= 1) ss += __shfl_xor(ss, m, 64);
    const float r = rsqrtf(ss + 1e-6f) * extra;
    *(float2*)(p + j) = make_float2(x.x * r, x.y * r);
}

// ---------------------------------------------------------------------------
// Gates: beta = sigmoid(b); decay = exp(-exp(A_log)*softplus(a + dt_bias))
// ---------------------------------------------------------------------------
__global__ __launch_bounds__(256) void gates(const float* __restrict__ ba,
                                             const float* __restrict__ dt_bias,
                                             const float* __restrict__ A_log,
                                             float* __restrict__ dec,
                                             float* __restrict__ bet) {
    const int i = blockIdx.x * 256 + threadIdx.x;  // T_LEN*16
    const int t = i >> 4;
    const int vh = i & 15;
    const int kh = vh >> 1;
    const int r = vh & 1;
    const float b = ba[t * 32 + kh * 4 + r];
    const float a = ba[t * 32 + kh * 4 + 2 + r];
    bet[i] = 1.f / (1.f + expf(-b));
    const float x = a + dt_bias[vh];
    const float sp = (x > 0.f) ? (x + log1pf(expf(-x))) : log1pf(expf(x));
    dec[i] = expf(-expf(A_log[vh]) * sp);
}

// ---------------------------------------------------------------------------
// Gated delta-rule recurrence, v4.
// 256 blocks x 64 threads.  kg = lane&7 (k rows kg*16..+16), vi = lane>>3.
// S[16] per lane; reductions over kg are 3 DPP ops (VALU rate, no LDS pipe).
// Prefetch ring of 4 slots, constant-indexed via full unroll of inner s-loop
// (early full unroll -> SROA promotes to registers; #pragma unroll 4 on a
//  single loop did NOT — arrays went to scratch/LDS in R3).
// sched_barrier(0) per step pins loads >=3 steps ahead of their use.
// ---------------------------------------------------------------------------
__global__ __launch_bounds__(64, 1) void recur(const float* __restrict__ qc,
                                               const float* __restrict__ kc,
                                               const float* __restrict__ vc,
                                               const float* __restrict__ dec,
                                               const float* __restrict__ bet,
                                               float* __restrict__ o) {
    const int b = blockIdx.x;
    const int h = b >> 4;        // value head 0..15
    const int vg = b & 15;       // v-group 0..15
    const int kh = h >> 1;       // key head
    const int lane = threadIdx.x;
    const int kg = lane & 7;     // low bits -> DPP-friendly reductions
    const int vi = lane >> 3;
    const int v = vg * 8 + vi;   // 0..127

    const float* kbase = kc + kh * 128 + kg * 16;
    const float* qbase = qc + kh * 128 + kg * 16;
    const float* vbase = vc + h * 128 + v;
    const float* dbase = dec + h;
    const float* bbase = bet + h;
    float* obase = o + h * 128 + v;

    float S[16];
#pragma unroll
    for (int j = 0; j < 16; ++j) S[j] = 0.f;

    float4 K[4][4], Q[4][4];
    float V[4], D[4], Bt[4];

#pragma unroll
    for (int s = 0; s < 4; ++s) {
        const float4* kp = (const float4*)(kbase + (size_t)s * 1024);
        const float4* qp = (const float4*)(qbase + (size_t)s * 1024);
#pragma unroll
        for (int i = 0; i < 4; ++i) { K[s][i] = kp[i]; Q[s][i] = qp[i]; }
        V[s] = vbase[(size_t)s * 2048];
        D[s] = dbase[(size_t)s * 16];
        Bt[s] = bbase[(size_t)s * 16];
    }

    for (int t0 = 0; t0 < T_LEN; t0 += 4) {
#pragma unroll
        for (int s = 0; s < 4; ++s) {   // full unroll: s is compile-time const
            const int t = t0 + s;
            // ---- compute step t from slot s ----
            float c0 = 0.f, c1 = 0.f, c2 = 0.f, c3 = 0.f;
#pragma unroll
            for (int i = 0; i < 4; ++i) {
                c0 = fmaf(K[s][i].x, S[4 * i + 0], c0);
                c1 = fmaf(K[s][i].y, S[4 * i + 1], c1);
                c2 = fmaf(K[s][i].z, S[4 * i + 2], c2);
                c3 = fmaf(K[s][i].w, S[4 * i + 3], c3);
            }
            const float kv = red8_dpp((c0 + c1) + (c2 + c3));
            const float d = D[s], be = Bt[s];
            const float delta = (V[s] - d * kv) * be;
            float o0 = 0.f, o1 = 0.f, o2 = 0.f, o3 = 0.f;
#pragma unroll
            for (int i = 0; i < 4; ++i) {
                S[4 * i + 0] = fmaf(S[4 * i + 0], d, K[s][i].x * delta); o0 = fmaf(Q[s][i].x, S[4 * i + 0], o0);
                S[4 * i + 1] = fmaf(S[4 * i + 1], d, K[s][i].y * delta); o1 = fmaf(Q[s][i].y, S[4 * i + 1], o1);
                S[4 * i + 2] = fmaf(S[4 * i + 2], d, K[s][i].z * delta); o2 = fmaf(Q[s][i].z, S[4 * i + 2], o2);
                S[4 * i + 3] = fmaf(S[4 * i + 3], d, K[s][i].w * delta); o3 = fmaf(Q[s][i].w, S[4 * i + 3], o3);
            }
            const float oo = red8_dpp((o0 + o1) + (o2 + o3));
            if (kg == 0) obase[(size_t)t * 2048] = oo;
            // ---- prefetch step t+4 into slot s ----
            if (t + 4 < T_LEN) {
                const float4* kp = (const float4*)(kbase + (size_t)(t + 4) * 1024);
                const float4* qp = (const float4*)(qbase + (size_t)(t + 4) * 1024);
#pragma unroll
                for (int i = 0; i < 4; ++i) { K[s][i] = kp[i]; Q[s][i] = qp[i]; }
                V[s] = vbase[(size_t)(t + 4) * 2048];
                D[s] = dbase[(size_t)(t + 4) * 16];
                Bt[s] = bbase[(size_t)(t + 4) * 16];
            }
            __builtin_amdgcn_sched_barrier(0);  // pin: loads can't sink across steps
        }
    }
}

// ---------------------------------------------------------------------------
// Gated RMSNorm: xf = o * silu(z); xn = xf * rsqrt(mean(xf^2)+eps) * w
// ---------------------------------------------------------------------------
__global__ __launch_bounds__(64) void gated_norm(const float* __restrict__ o,
                                                 const float* __restrict__ qkvz,
                                                 const float* __restrict__ nw,
                                                 float* __restrict__ xn) {
    const int b = blockIdx.x;
    const int t = b >> 4;
    const int vh = b & 15;
    const int kh = vh >> 1;
    const int r = vh & 1;
    const float* op = o + (size_t)t * 2048 + vh * 128;
    const float* zp = qkvz + (size_t)t * QKVZ_N + kh * 768 + 512 + r * 128;
    const int j = threadIdx.x * 2;
    const float2 ov = *(const float2*)(op + j);
    const float2 zv = *(const float2*)(zp + j);
    const float f0 = ov.x * zv.x / (1.f + expf(-zv.x));
    const float f1 = ov.y * zv.y / (1.f + expf(-zv.y));
    float ss = f0 * f0 + f1 * f1;
#pragma unroll
    for (int m = 1; m < 64; m <<= 1) ss += __shfl_xor(ss, m, 64);
    const float rs = rsqrtf(ss * (1.f / 128.f) + 1e-6f);
    float* xp = xn + (size_t)t * 2048 + vh * 128;
    *(float2*)(xp + j) = make_float2(f0 * rs * nw[j], f1 * rs * nw[j + 1]);
}

// ---------------------------------------------------------------------------
extern "C" void kernel_launch(void* const* d_in, const int* in_sizes, int n_in,
                              void* d_out, int out_size, void* d_ws, size_t ws_size,
                              hipStream_t stream) {
    const float* hidden  = (const float*)d_in[0];
    const float* w_qkvz  = (const float*)d_in[1];
    const float* w_ba    = (const float*)d_in[2];
    const float* conv_w  = (const float*)d_in[3];
    const float* dt_bias = (const float*)d_in[4];
    const float* A_log   = (const float*)d_in[5];
    const float* norm_w  = (const float*)d_in[6];
    const float* w_out   = (const float*)d_in[7];
    float* out = (float*)d_out;

    float* ws   = (float*)d_ws;
    float* qkvz = ws;                  // 1024*6144
    float* ba   = qkvz + 6291456;      // 1024*32
    float* qc   = ba + 32768;          // 1024*1024
    float* kc   = qc + 1048576;        // 1024*1024
    float* vc   = kc + 1048576;        // 1024*2048
    float* dcy  = vc + 2097152;        // 1024*16
    float* bet  = dcy + 16384;         // 1024*16
    float* o    = bet + 16384;         // 1024*2048
    float* xn   = o + 2097152;         // 1024*2048

    gemm_bt<<<dim3(QKVZ_N / 64, T_LEN / 64), 256, 0, stream>>>(hidden, w_qkvz, qkvz,
                                                               T_LEN, QKVZ_N, HIDDEN);
    gemm_bt<<<dim3(1, T_LEN / 64), 256, 0, stream>>>(hidden, w_ba, ba, T_LEN, 32, HIDDEN);
    conv_silu<<<(T_LEN * 4096) / 256, 256, 0, stream>>>(qkvz, conv_w, qc, kc, vc);
    l2norm_qk<<<T_LEN * 16, 64, 0, stream>>>(qc, kc);
    gates<<<(T_LEN * 16) / 256, 256, 0, stream>>>(ba, dt_bias, A_log, dcy, bet);
    recur<<<256, 64, 0, stream>>>(qc, kc, vc, dcy, bet, o);
    gated_norm<<<T_LEN * 16, 64, 0, stream>>>(o, qkvz, norm_w, xn);
    gemm_bt<<<dim3(VAL_DIM / 64, T_LEN / 64), 256, 0, stream>>>(xn, w_out, out,
                                                                T_LEN, VAL_DIM, HIDDEN);
}

// Round 5
// 763.765 us; speedup vs baseline: 2.0438x; 1.3850x over previous
//
#include <hip/hip_runtime.h>
#include <math.h>

// ---------------- problem constants ----------------
#define T_LEN   1024
#define HIDDEN  2048
#define NUMV    16
#define NUMK    8
#define HKD     128
#define QKVZ_N  6144   // 2*KEY_DIM + 2*VALUE_DIM
#define KEY_DIM 1024
#define VAL_DIM 2048

typedef _Float16 half8 __attribute__((ext_vector_type(8)));
typedef float floatx4 __attribute__((ext_vector_type(4)));

__device__ __forceinline__ float sigmoidf_(float x) { return 1.f / (1.f + expf(-x)); }

// DPP lane-exchange at VALU rate
template <int CTRL>
__device__ __forceinline__ float dpp_mov(float x) {
    return __int_as_float(
        __builtin_amdgcn_update_dpp(0, __float_as_int(x), CTRL, 0xF, 0xF, true));
}
// reduce over kg = lane&7: xor1 (quad_perm 0xB1), xor2 (quad_perm 0x4E),
// then row_half_mirror (0x141) pairs across the two 4-groups.
__device__ __forceinline__ float red8_dpp(float x) {
    x += dpp_mov<0xB1>(x);
    x += dpp_mov<0x4E>(x);
    x += dpp_mov<0x141>(x);
    return x;
}

// ---------------------------------------------------------------------------
// fp16-MFMA GEMM: C[M,N] = A[M,K] * W[N,K]^T, fp32 in/out, fp16 compute,
// fp32 accumulate.  128x128 tile, BK=32, 256 threads = 4 waves (2x2), each
// wave 4x4 fragments of v_mfma_f32_16x16x32_f16.
// LDS layout: 16B chunks, chunk(r,kq) at index r*4 + (kq ^ (r&3)):
//   staging ds_write_b128 conflict-free, fragment ds_read_b128 worst 2-way.
// Requires M%128==0, N%128==0, K%32==0.
// ---------------------------------------------------------------------------
__global__ __launch_bounds__(256) void gemm_f16(const float* __restrict__ A,
                                                const float* __restrict__ W,
                                                float* __restrict__ C,
                                                int M, int N, int K) {
    __shared__ __align__(16) _Float16 Ah[512 * 8];  // 128 rows x 32 k
    __shared__ __align__(16) _Float16 Bh[512 * 8];

    const int t = threadIdx.x;
    const int m0 = blockIdx.x * 128;   // m-block fastest -> W-tile L2 reuse
    const int n0 = blockIdx.y * 128;

    // staging coords: thread -> (row r0/r0+64, k-oct kq)
    const int kq = t & 3;
    const int r0 = t >> 2;             // 0..63

    // compute coords
    const int wave = t >> 6;
    const int lane = t & 63;
    const int wr = (wave >> 1) * 64;   // wave row offset
    const int wc = (wave & 1) * 64;    // wave col offset
    const int l15 = lane & 15;
    const int quad = lane >> 4;

    floatx4 acc[4][4];
#pragma unroll
    for (int i = 0; i < 4; ++i)
#pragma unroll
        for (int j = 0; j < 4; ++j) acc[i][j] = 0;

    for (int k0 = 0; k0 < K; k0 += 32) {
        // ---- global loads (regs) ----
        float4 ag[2][2], bg[2][2];
#pragma unroll
        for (int p = 0; p < 2; ++p) {
            const int r = r0 + p * 64;
            const float4* ap = (const float4*)(A + (size_t)(m0 + r) * K + k0 + kq * 8);
            const float4* bp = (const float4*)(W + (size_t)(n0 + r) * K + k0 + kq * 8);
            ag[p][0] = ap[0]; ag[p][1] = ap[1];
            bg[p][0] = bp[0]; bg[p][1] = bp[1];
        }
        __syncthreads();   // previous iter's LDS reads done
        // ---- convert + swizzled LDS write ----
#pragma unroll
        for (int p = 0; p < 2; ++p) {
            const int r = r0 + p * 64;
            const int chunk = r * 4 + (kq ^ (r & 3));
            half8 ha, hb;
            ha[0] = (_Float16)ag[p][0].x; ha[1] = (_Float16)ag[p][0].y;
            ha[2] = (_Float16)ag[p][0].z; ha[3] = (_Float16)ag[p][0].w;
            ha[4] = (_Float16)ag[p][1].x; ha[5] = (_Float16)ag[p][1].y;
            ha[6] = (_Float16)ag[p][1].z; ha[7] = (_Float16)ag[p][1].w;
            hb[0] = (_Float16)bg[p][0].x; hb[1] = (_Float16)bg[p][0].y;
            hb[2] = (_Float16)bg[p][0].z; hb[3] = (_Float16)bg[p][0].w;
            hb[4] = (_Float16)bg[p][1].x; hb[5] = (_Float16)bg[p][1].y;
            hb[6] = (_Float16)bg[p][1].z; hb[7] = (_Float16)bg[p][1].w;
            *(half8*)&Ah[chunk * 8] = ha;
            *(half8*)&Bh[chunk * 8] = hb;
        }
        __syncthreads();
        // ---- fragments + MFMA ----
        half8 af[4], bf[4];
#pragma unroll
        for (int mt = 0; mt < 4; ++mt) {
            const int m = wr + mt * 16 + l15;
            af[mt] = *(const half8*)&Ah[(m * 4 + (quad ^ (m & 3))) * 8];
        }
#pragma unroll
        for (int nt = 0; nt < 4; ++nt) {
            const int n = wc + nt * 16 + l15;
            bf[nt] = *(const half8*)&Bh[(n * 4 + (quad ^ (n & 3))) * 8];
        }
#pragma unroll
        for (int mt = 0; mt < 4; ++mt)
#pragma unroll
            for (int nt = 0; nt < 4; ++nt)
                acc[mt][nt] = __builtin_amdgcn_mfma_f32_16x16x32_f16(
                    af[mt], bf[nt], acc[mt][nt], 0, 0, 0);
    }
    // ---- epilogue: C/D layout col=lane&15, row=quad*4+reg ----
#pragma unroll
    for (int mt = 0; mt < 4; ++mt) {
        const int col = n0 + wc + 0 * 16 + l15;  // per-nt below
#pragma unroll
        for (int nt = 0; nt < 4; ++nt) {
            const int c = n0 + wc + nt * 16 + l15;
#pragma unroll
            for (int reg = 0; reg < 4; ++reg) {
                const int r = m0 + wr + mt * 16 + quad * 4 + reg;
                C[(size_t)r * N + c] = acc[mt][nt][reg];
            }
        }
        (void)col;
    }
}

// ---------------------------------------------------------------------------
// fp32 GEMM (kept for the tiny ba projection, N=32)
// ---------------------------------------------------------------------------
__global__ __launch_bounds__(256) void gemm_bt(const float* __restrict__ A,
                                               const float* __restrict__ B,
                                               float* __restrict__ C,
                                               int M, int N, int K) {
    __shared__ float As[16][68];
    __shared__ float Bs[16][68];
    const int tid = threadIdx.x;
    const int m0 = blockIdx.y * 64;
    const int n0 = blockIdx.x * 64;
    const int tx = tid & 15;
    const int ty = tid >> 4;
    const int lr = tid >> 2;
    const int lk = (tid & 3) << 2;

    float acc[4][4];
#pragma unroll
    for (int i = 0; i < 4; ++i)
#pragma unroll
        for (int j = 0; j < 4; ++j) acc[i][j] = 0.f;

    for (int k0 = 0; k0 < K; k0 += 16) {
        float4 av = *(const float4*)(A + (size_t)(m0 + lr) * K + k0 + lk);
        float4 bv = make_float4(0.f, 0.f, 0.f, 0.f);
        if (n0 + lr < N) bv = *(const float4*)(B + (size_t)(n0 + lr) * K + k0 + lk);
        __syncthreads();
        As[lk + 0][lr] = av.x; As[lk + 1][lr] = av.y; As[lk + 2][lr] = av.z; As[lk + 3][lr] = av.w;
        Bs[lk + 0][lr] = bv.x; Bs[lk + 1][lr] = bv.y; Bs[lk + 2][lr] = bv.z; Bs[lk + 3][lr] = bv.w;
        __syncthreads();
#pragma unroll
        for (int kk = 0; kk < 16; ++kk) {
            float4 a4 = *(const float4*)&As[kk][ty << 2];
            float4 b4 = *(const float4*)&Bs[kk][tx << 2];
            const float ar[4] = {a4.x, a4.y, a4.z, a4.w};
            const float br[4] = {b4.x, b4.y, b4.z, b4.w};
#pragma unroll
            for (int i = 0; i < 4; ++i)
#pragma unroll
                for (int j = 0; j < 4; ++j) acc[i][j] = fmaf(ar[i], br[j], acc[i][j]);
        }
    }
#pragma unroll
    for (int i = 0; i < 4; ++i) {
        const int row = m0 + (ty << 2) + i;
        const int col = n0 + (tx << 2);
        if (col + 3 < N) {
            *(float4*)(C + (size_t)row * N + col) =
                make_float4(acc[i][0], acc[i][1], acc[i][2], acc[i][3]);
        } else {
#pragma unroll
            for (int j = 0; j < 4; ++j)
                if (col + j < N) C[(size_t)row * N + col + j] = acc[i][j];
        }
    }
}

// ---------------------------------------------------------------------------
// Depthwise causal conv1d (K=4) + SiLU over mixed [q|k|v] channel layout.
// ---------------------------------------------------------------------------
__global__ __launch_bounds__(256) void conv_silu(const float* __restrict__ qkvz,
                                                 const float* __restrict__ conv_w,
                                                 float* __restrict__ qc,
                                                 float* __restrict__ kc,
                                                 float* __restrict__ vc) {
    const int idx = blockIdx.x * 256 + threadIdx.x;
    const int t = idx >> 12;
    const int c = idx & 4095;
    int col;
    float* dst;
    if (c < 1024) {
        col = ((c >> 7) * 768) + (c & 127);
        dst = qc + t * 1024 + c;
    } else if (c < 2048) {
        const int cc = c - 1024;
        col = ((cc >> 7) * 768) + 128 + (cc & 127);
        dst = kc + t * 1024 + cc;
    } else {
        const int cc = c - 2048;
        col = ((cc >> 8) * 768) + 256 + (cc & 255);
        dst = vc + t * 2048 + cc;
    }
    const float w0 = conv_w[c * 4 + 0];
    const float w1 = conv_w[c * 4 + 1];
    const float w2 = conv_w[c * 4 + 2];
    const float w3 = conv_w[c * 4 + 3];
    float acc = qkvz[(size_t)t * QKVZ_N + col] * w3;
    if (t >= 1) acc = fmaf(qkvz[(size_t)(t - 1) * QKVZ_N + col], w2, acc);
    if (t >= 2) acc = fmaf(qkvz[(size_t)(t - 2) * QKVZ_N + col], w1, acc);
    if (t >= 3) acc = fmaf(qkvz[(size_t)(t - 3) * QKVZ_N + col], w0, acc);
    *dst = acc * sigmoidf_(acc);
}

// ---------------------------------------------------------------------------
// L2 normalize q and k per (t, k-head); fold scale=HK^-0.5 into q.
// ---------------------------------------------------------------------------
__global__ __launch_bounds__(64) void l2norm_qk(float* __restrict__ qc, float* __restrict__ kc) {
    const int b = blockIdx.x;
    const int t = b >> 4;
    const int hh = b & 15;
    float* p;
    float extra;
    if (hh < 8) { p = qc + t * 1024 + hh * 128; extra = 0.08838834764831845f; }
    else        { p = kc + t * 1024 + (hh - 8) * 128; extra = 1.f; }
    const int j = threadIdx.x * 2;
    float2 x = *(const float2*)(p + j);
    float ss = x.x * x.x + x.y * x.y;
#pragma unroll
    for (int m = 1; m < 64; m <<= 1) ss += __shfl_xor(ss, m, 64);
    const float r = rsqrtf(ss + 1e-6f) * extra;
    *(float2*)(p + j) = make_float2(x.x * r, x.y * r);
}

// ---------------------------------------------------------------------------
// Gates: beta = sigmoid(b); decay = exp(-exp(A_log)*softplus(a + dt_bias))
// ---------------------------------------------------------------------------
__global__ __launch_bounds__(256) void gates(const float* __restrict__ ba,
                                             const float* __restrict__ dt_bias,
                                             const float* __restrict__ A_log,
                                             float* __restrict__ dec,
                                             float* __restrict__ bet) {
    const int i = blockIdx.x * 256 + threadIdx.x;
    const int t = i >> 4;
    const int vh = i & 15;
    const int kh = vh >> 1;
    const int r = vh & 1;
    const float b = ba[t * 32 + kh * 4 + r];
    const float a = ba[t * 32 + kh * 4 + 2 + r];
    bet[i] = 1.f / (1.f + expf(-b));
    const float x = a + dt_bias[vh];
    const float sp = (x > 0.f) ? (x + log1pf(expf(-x))) : log1pf(expf(x));
    dec[i] = expf(-expf(A_log[vh]) * sp);
}

// ---------------------------------------------------------------------------
// Gated delta-rule recurrence, v4 (unchanged from R4).
// ---------------------------------------------------------------------------
__global__ __launch_bounds__(64, 1) void recur(const float* __restrict__ qc,
                                               const float* __restrict__ kc,
                                               const float* __restrict__ vc,
                                               const float* __restrict__ dec,
                                               const float* __restrict__ bet,
                                               float* __restrict__ o) {
    const int b = blockIdx.x;
    const int h = b >> 4;
    const int vg = b & 15;
    const int kh = h >> 1;
    const int lane = threadIdx.x;
    const int kg = lane & 7;
    const int vi = lane >> 3;
    const int v = vg * 8 + vi;

    const float* kbase = kc + kh * 128 + kg * 16;
    const float* qbase = qc + kh * 128 + kg * 16;
    const float* vbase = vc + h * 128 + v;
    const float* dbase = dec + h;
    const float* bbase = bet + h;
    float* obase = o + h * 128 + v;

    float S[16];
#pragma unroll
    for (int j = 0; j < 16; ++j) S[j] = 0.f;

    float4 K[4][4], Q[4][4];
    float V[4], D[4], Bt[4];

#pragma unroll
    for (int s = 0; s < 4; ++s) {
        const float4* kp = (const float4*)(kbase + (size_t)s * 1024);
        const float4* qp = (const float4*)(qbase + (size_t)s * 1024);
#pragma unroll
        for (int i = 0; i < 4; ++i) { K[s][i] = kp[i]; Q[s][i] = qp[i]; }
        V[s] = vbase[(size_t)s * 2048];
        D[s] = dbase[(size_t)s * 16];
        Bt[s] = bbase[(size_t)s * 16];
    }

    for (int t0 = 0; t0 < T_LEN; t0 += 4) {
#pragma unroll
        for (int s = 0; s < 4; ++s) {
            const int t = t0 + s;
            float c0 = 0.f, c1 = 0.f, c2 = 0.f, c3 = 0.f;
#pragma unroll
            for (int i = 0; i < 4; ++i) {
                c0 = fmaf(K[s][i].x, S[4 * i + 0], c0);
                c1 = fmaf(K[s][i].y, S[4 * i + 1], c1);
                c2 = fmaf(K[s][i].z, S[4 * i + 2], c2);
                c3 = fmaf(K[s][i].w, S[4 * i + 3], c3);
            }
            const float kv = red8_dpp((c0 + c1) + (c2 + c3));
            const float d = D[s], be = Bt[s];
            const float delta = (V[s] - d * kv) * be;
            float o0 = 0.f, o1 = 0.f, o2 = 0.f, o3 = 0.f;
#pragma unroll
            for (int i = 0; i < 4; ++i) {
                S[4 * i + 0] = fmaf(S[4 * i + 0], d, K[s][i].x * delta); o0 = fmaf(Q[s][i].x, S[4 * i + 0], o0);
                S[4 * i + 1] = fmaf(S[4 * i + 1], d, K[s][i].y * delta); o1 = fmaf(Q[s][i].y, S[4 * i + 1], o1);
                S[4 * i + 2] = fmaf(S[4 * i + 2], d, K[s][i].z * delta); o2 = fmaf(Q[s][i].z, S[4 * i + 2], o2);
                S[4 * i + 3] = fmaf(S[4 * i + 3], d, K[s][i].w * delta); o3 = fmaf(Q[s][i].w, S[4 * i + 3], o3);
            }
            const float oo = red8_dpp((o0 + o1) + (o2 + o3));
            if (kg == 0) obase[(size_t)t * 2048] = oo;
            if (t + 4 < T_LEN) {
                const float4* kp = (const float4*)(kbase + (size_t)(t + 4) * 1024);
                const float4* qp = (const float4*)(qbase + (size_t)(t + 4) * 1024);
#pragma unroll
                for (int i = 0; i < 4; ++i) { K[s][i] = kp[i]; Q[s][i] = qp[i]; }
                V[s] = vbase[(size_t)(t + 4) * 2048];
                D[s] = dbase[(size_t)(t + 4) * 16];
                Bt[s] = bbase[(size_t)(t + 4) * 16];
            }
            __builtin_amdgcn_sched_barrier(0);
        }
    }
}

// ---------------------------------------------------------------------------
// Gated RMSNorm: xf = o * silu(z); xn = xf * rsqrt(mean(xf^2)+eps) * w
// ---------------------------------------------------------------------------
__global__ __launch_bounds__(64) void gated_norm(const float* __restrict__ o,
                                                 const float* __restrict__ qkvz,
                                                 const float* __restrict__ nw,
                                                 float* __restrict__ xn) {
    const int b = blockIdx.x;
    const int t = b >> 4;
    const int vh = b & 15;
    const int kh = vh >> 1;
    const int r = vh & 1;
    const float* op = o + (size_t)t * 2048 + vh * 128;
    const float* zp = qkvz + (size_t)t * QKVZ_N + kh * 768 + 512 + r * 128;
    const int j = threadIdx.x * 2;
    const float2 ov = *(const float2*)(op + j);
    const float2 zv = *(const float2*)(zp + j);
    const float f0 = ov.x * zv.x / (1.f + expf(-zv.x));
    const float f1 = ov.y * zv.y / (1.f + expf(-zv.y));
    float ss = f0 * f0 + f1 * f1;
#pragma unroll
    for (int m = 1; m < 64; m <<= 1) ss += __shfl_xor(ss, m, 64);
    const float rs = rsqrtf(ss * (1.f / 128.f) + 1e-6f);
    float* xp = xn + (size_t)t * 2048 + vh * 128;
    *(float2*)(xp + j) = make_float2(f0 * rs * nw[j], f1 * rs * nw[j + 1]);
}

// ---------------------------------------------------------------------------
extern "C" void kernel_launch(void* const* d_in, const int* in_sizes, int n_in,
                              void* d_out, int out_size, void* d_ws, size_t ws_size,
                              hipStream_t stream) {
    const float* hidden  = (const float*)d_in[0];
    const float* w_qkvz  = (const float*)d_in[1];
    const float* w_ba    = (const float*)d_in[2];
    const float* conv_w  = (const float*)d_in[3];
    const float* dt_bias = (const float*)d_in[4];
    const float* A_log   = (const float*)d_in[5];
    const float* norm_w  = (const float*)d_in[6];
    const float* w_out   = (const float*)d_in[7];
    float* out = (float*)d_out;

    float* ws   = (float*)d_ws;
    float* qkvz = ws;                  // 1024*6144
    float* ba   = qkvz + 6291456;      // 1024*32
    float* qc   = ba + 32768;          // 1024*1024
    float* kc   = qc + 1048576;        // 1024*1024
    float* vc   = kc + 1048576;        // 1024*2048
    float* dcy  = vc + 2097152;        // 1024*16
    float* bet  = dcy + 16384;         // 1024*16
    float* o    = bet + 16384;         // 1024*2048
    float* xn   = o + 2097152;         // 1024*2048

    gemm_f16<<<dim3(T_LEN / 128, QKVZ_N / 128), 256, 0, stream>>>(hidden, w_qkvz, qkvz,
                                                                  T_LEN, QKVZ_N, HIDDEN);
    gemm_bt<<<dim3(1, T_LEN / 64), 256, 0, stream>>>(hidden, w_ba, ba, T_LEN, 32, HIDDEN);
    conv_silu<<<(T_LEN * 4096) / 256, 256, 0, stream>>>(qkvz, conv_w, qc, kc, vc);
    l2norm_qk<<<T_LEN * 16, 64, 0, stream>>>(qc, kc);
    gates<<<(T_LEN * 16) / 256, 256, 0, stream>>>(ba, dt_bias, A_log, dcy, bet);
    recur<<<256, 64, 0, stream>>>(qc, kc, vc, dcy, bet, o);
    gated_norm<<<T_LEN * 16, 64, 0, stream>>>(o, qkvz, norm_w, xn);
    gemm_f16<<<dim3(T_LEN / 128, VAL_DIM / 128), 256, 0, stream>>>(xn, w_out, out,
                                                                   T_LEN, VAL_DIM, HIDDEN);
}

// Round 6
// 572.747 us; speedup vs baseline: 2.7255x; 1.3335x over previous
//
#include <hip/hip_runtime.h>
#include <math.h>

// ---------------- problem constants ----------------
#define T_LEN   1024
#define HIDDEN  2048
#define QKVZ_N  6144   // 2*KEY_DIM + 2*VALUE_DIM
#define VAL_DIM 2048

typedef _Float16 half8 __attribute__((ext_vector_type(8)));
typedef _Float16 half4 __attribute__((ext_vector_type(4)));
typedef _Float16 half2t __attribute__((ext_vector_type(2)));
typedef float floatx4 __attribute__((ext_vector_type(4)));

__device__ __forceinline__ float sigmoidf_(float x) { return 1.f / (1.f + expf(-x)); }

// ---------------------------------------------------------------------------
// fp16-MFMA GEMM: C[M,N] = A[M,K] * W[N,K]^T  (fp32 in/out, fp16 MFMA)
// 128x128 tile, BK=32, 4 waves 2x2, 4x4 frags of v_mfma_f32_16x16x32_f16.
// ---------------------------------------------------------------------------
__global__ __launch_bounds__(256) void gemm_f16(const float* __restrict__ A,
                                                const float* __restrict__ W,
                                                float* __restrict__ C,
                                                int M, int N, int K) {
    __shared__ __align__(16) _Float16 Ah[512 * 8];
    __shared__ __align__(16) _Float16 Bh[512 * 8];

    const int t = threadIdx.x;
    const int m0 = blockIdx.x * 128;
    const int n0 = blockIdx.y * 128;
    const int kq = t & 3;
    const int r0 = t >> 2;
    const int wave = t >> 6;
    const int lane = t & 63;
    const int wr = (wave >> 1) * 64;
    const int wc = (wave & 1) * 64;
    const int l15 = lane & 15;
    const int quad = lane >> 4;

    floatx4 acc[4][4];
#pragma unroll
    for (int i = 0; i < 4; ++i)
#pragma unroll
        for (int j = 0; j < 4; ++j) acc[i][j] = 0;

    for (int k0 = 0; k0 < K; k0 += 32) {
        float4 ag[2][2], bg[2][2];
#pragma unroll
        for (int p = 0; p < 2; ++p) {
            const int r = r0 + p * 64;
            const float4* ap = (const float4*)(A + (size_t)(m0 + r) * K + k0 + kq * 8);
            const float4* bp = (const float4*)(W + (size_t)(n0 + r) * K + k0 + kq * 8);
            ag[p][0] = ap[0]; ag[p][1] = ap[1];
            bg[p][0] = bp[0]; bg[p][1] = bp[1];
        }
        __syncthreads();
#pragma unroll
        for (int p = 0; p < 2; ++p) {
            const int r = r0 + p * 64;
            const int chunk = r * 4 + (kq ^ (r & 3));
            half8 ha, hb;
            ha[0] = (_Float16)ag[p][0].x; ha[1] = (_Float16)ag[p][0].y;
            ha[2] = (_Float16)ag[p][0].z; ha[3] = (_Float16)ag[p][0].w;
            ha[4] = (_Float16)ag[p][1].x; ha[5] = (_Float16)ag[p][1].y;
            ha[6] = (_Float16)ag[p][1].z; ha[7] = (_Float16)ag[p][1].w;
            hb[0] = (_Float16)bg[p][0].x; hb[1] = (_Float16)bg[p][0].y;
            hb[2] = (_Float16)bg[p][0].z; hb[3] = (_Float16)bg[p][0].w;
            hb[4] = (_Float16)bg[p][1].x; hb[5] = (_Float16)bg[p][1].y;
            hb[6] = (_Float16)bg[p][1].z; hb[7] = (_Float16)bg[p][1].w;
            *(half8*)&Ah[chunk * 8] = ha;
            *(half8*)&Bh[chunk * 8] = hb;
        }
        __syncthreads();
        half8 af[4], bf[4];
#pragma unroll
        for (int mt = 0; mt < 4; ++mt) {
            const int m = wr + mt * 16 + l15;
            af[mt] = *(const half8*)&Ah[(m * 4 + (quad ^ (m & 3))) * 8];
        }
#pragma unroll
        for (int nt = 0; nt < 4; ++nt) {
            const int n = wc + nt * 16 + l15;
            bf[nt] = *(const half8*)&Bh[(n * 4 + (quad ^ (n & 3))) * 8];
        }
#pragma unroll
        for (int mt = 0; mt < 4; ++mt)
#pragma unroll
            for (int nt = 0; nt < 4; ++nt)
                acc[mt][nt] = __builtin_amdgcn_mfma_f32_16x16x32_f16(
                    af[mt], bf[nt], acc[mt][nt], 0, 0, 0);
    }
#pragma unroll
    for (int mt = 0; mt < 4; ++mt)
#pragma unroll
        for (int nt = 0; nt < 4; ++nt) {
            const int c = n0 + wc + nt * 16 + l15;
#pragma unroll
            for (int reg = 0; reg < 4; ++reg) {
                const int r = m0 + wr + mt * 16 + quad * 4 + reg;
                C[(size_t)r * N + c] = acc[mt][nt][reg];
            }
        }
}

// ---------------------------------------------------------------------------
// fp32 GEMM for the tiny ba projection (N=32)
// ---------------------------------------------------------------------------
__global__ __launch_bounds__(256) void gemm_bt(const float* __restrict__ A,
                                               const float* __restrict__ B,
                                               float* __restrict__ C,
                                               int M, int N, int K) {
    __shared__ float As[16][68];
    __shared__ float Bs[16][68];
    const int tid = threadIdx.x;
    const int m0 = blockIdx.y * 64;
    const int n0 = blockIdx.x * 64;
    const int tx = tid & 15;
    const int ty = tid >> 4;
    const int lr = tid >> 2;
    const int lk = (tid & 3) << 2;

    float acc[4][4];
#pragma unroll
    for (int i = 0; i < 4; ++i)
#pragma unroll
        for (int j = 0; j < 4; ++j) acc[i][j] = 0.f;

    for (int k0 = 0; k0 < K; k0 += 16) {
        float4 av = *(const float4*)(A + (size_t)(m0 + lr) * K + k0 + lk);
        float4 bv = make_float4(0.f, 0.f, 0.f, 0.f);
        if (n0 + lr < N) bv = *(const float4*)(B + (size_t)(n0 + lr) * K + k0 + lk);
        __syncthreads();
        As[lk + 0][lr] = av.x; As[lk + 1][lr] = av.y; As[lk + 2][lr] = av.z; As[lk + 3][lr] = av.w;
        Bs[lk + 0][lr] = bv.x; Bs[lk + 1][lr] = bv.y; Bs[lk + 2][lr] = bv.z; Bs[lk + 3][lr] = bv.w;
        __syncthreads();
#pragma unroll
        for (int kk = 0; kk < 16; ++kk) {
            float4 a4 = *(const float4*)&As[kk][ty << 2];
            float4 b4 = *(const float4*)&Bs[kk][tx << 2];
            const float ar[4] = {a4.x, a4.y, a4.z, a4.w};
            const float br[4] = {b4.x, b4.y, b4.z, b4.w};
#pragma unroll
            for (int i = 0; i < 4; ++i)
#pragma unroll
                for (int j = 0; j < 4; ++j) acc[i][j] = fmaf(ar[i], br[j], acc[i][j]);
        }
    }
#pragma unroll
    for (int i = 0; i < 4; ++i) {
        const int row = m0 + (ty << 2) + i;
        const int col = n0 + (tx << 2);
#pragma unroll
        for (int j = 0; j < 4; ++j)
            if (col + j < N) C[(size_t)row * N + col + j] = acc[i][j];
    }
}

// ---------------------------------------------------------------------------
// Depthwise causal conv1d (K=4) + SiLU; outputs fp16 q/k/v.
// qkvz row layout per k-head block of 768: [q 128 | k 128 | v 256 | z 256]
// ---------------------------------------------------------------------------
__global__ __launch_bounds__(256) void conv_silu(const float* __restrict__ qkvz,
                                                 const float* __restrict__ conv_w,
                                                 _Float16* __restrict__ qc,
                                                 _Float16* __restrict__ kc,
                                                 _Float16* __restrict__ vc) {
    const int idx = blockIdx.x * 256 + threadIdx.x;
    const int t = idx >> 12;
    const int c = idx & 4095;
    int col;
    _Float16* dst;
    if (c < 1024) {
        col = ((c >> 7) * 768) + (c & 127);
        dst = qc + t * 1024 + c;
    } else if (c < 2048) {
        const int cc = c - 1024;
        col = ((cc >> 7) * 768) + 128 + (cc & 127);
        dst = kc + t * 1024 + cc;
    } else {
        const int cc = c - 2048;
        col = ((cc >> 8) * 768) + 256 + (cc & 255);
        dst = vc + t * 2048 + cc;
    }
    const float w0 = conv_w[c * 4 + 0];
    const float w1 = conv_w[c * 4 + 1];
    const float w2 = conv_w[c * 4 + 2];
    const float w3 = conv_w[c * 4 + 3];
    float acc = qkvz[(size_t)t * QKVZ_N + col] * w3;
    if (t >= 1) acc = fmaf(qkvz[(size_t)(t - 1) * QKVZ_N + col], w2, acc);
    if (t >= 2) acc = fmaf(qkvz[(size_t)(t - 2) * QKVZ_N + col], w1, acc);
    if (t >= 3) acc = fmaf(qkvz[(size_t)(t - 3) * QKVZ_N + col], w0, acc);
    *dst = (_Float16)(acc * sigmoidf_(acc));
}

// ---------------------------------------------------------------------------
// L2 normalize q and k per (t, k-head) on fp16 buffers; fold 128^-0.5 into q.
// ---------------------------------------------------------------------------
__global__ __launch_bounds__(64) void l2norm_qk(_Float16* __restrict__ qc,
                                                _Float16* __restrict__ kc) {
    const int b = blockIdx.x;
    const int t = b >> 4;
    const int hh = b & 15;
    _Float16* p;
    float extra;
    if (hh < 8) { p = qc + t * 1024 + hh * 128; extra = 0.08838834764831845f; }
    else        { p = kc + t * 1024 + (hh - 8) * 128; extra = 1.f; }
    const int j = threadIdx.x * 2;
    half2t x = *(const half2t*)(p + j);
    const float x0 = (float)x[0], x1 = (float)x[1];
    float ss = x0 * x0 + x1 * x1;
#pragma unroll
    for (int m = 1; m < 64; m <<= 1) ss += __shfl_xor(ss, m, 64);
    const float r = rsqrtf(ss + 1e-6f) * extra;
    half2t y; y[0] = (_Float16)(x0 * r); y[1] = (_Float16)(x1 * r);
    *(half2t*)(p + j) = y;
}

// ---------------------------------------------------------------------------
// Gates: beta = sigmoid(b); lgd = log-decay = -exp(A_log)*softplus(a+dt_bias)
// ---------------------------------------------------------------------------
__global__ __launch_bounds__(256) void gates(const float* __restrict__ ba,
                                             const float* __restrict__ dt_bias,
                                             const float* __restrict__ A_log,
                                             float* __restrict__ lgd,
                                             float* __restrict__ bet) {
    const int i = blockIdx.x * 256 + threadIdx.x;
    const int t = i >> 4;
    const int vh = i & 15;
    const int kh = vh >> 1;
    const int r = vh & 1;
    const float b = ba[t * 32 + kh * 4 + r];
    const float a = ba[t * 32 + kh * 4 + 2 + r];
    bet[i] = 1.f / (1.f + expf(-b));
    const float x = a + dt_bias[vh];
    const float sp = (x > 0.f) ? (x + log1pf(expf(-x))) : log1pf(expf(x));
    lgd[i] = -expf(A_log[vh]) * sp;
}

// ---------------------------------------------------------------------------
// chunk_prep: per (chunk c, v-head h) compute, fully parallel (256 blocks):
//   G = cumsum(log-decay), A[t,i] = b_t e^{Gt-Gi} (k_t.k_i)  (strict tril)
//   W = (I+A)^-1 (b*V), U = (I+A)^-1 (b*gamma*K)   [delta = W - U S0]
//   L[t,i] = e^{Gt-Gi} (q_t.k_i) (tril incl diag), Khat^T, gamma*Q, gamma_C
// Outputs fp16 blob per chunk-head: U[64x128] Wt[128x64] Kh[128x64]
//   Qg[64x128] L[64x64]  (36864 halves)
// ---------------------------------------------------------------------------
__global__ __launch_bounds__(256) void chunk_prep(
    const _Float16* __restrict__ qch, const _Float16* __restrict__ kch,
    const _Float16* __restrict__ vch, const float* __restrict__ lgd,
    const float* __restrict__ bet, _Float16* __restrict__ CH,
    float* __restrict__ gamC) {
    const int blk = blockIdx.x;
    const int c = blk >> 4, h = blk & 15, kh = h >> 1;
    const int c0 = c * 64;
    const int tid = threadIdx.x, lane = tid & 63, wave = tid >> 6;
    const int l15 = lane & 15, quad = lane >> 4;

    __shared__ __align__(16) _Float16 Ksh[8192];  // [t][kc sw][8]
    __shared__ __align__(16) _Float16 Qsh[8192];
    __shared__ float Amat[64 * 65];
    __shared__ float Gs[64], Bets[64], Gam[64];

    // stage K,Q chunk slices, swizzled chunk(t,kc) = t*16 + (kc ^ (t&15))
    {
        const int t = tid >> 2, kc0 = (tid & 3) * 4;
        const size_t gb = (size_t)(c0 + t) * 1024 + kh * 128;
#pragma unroll
        for (int i = 0; i < 4; ++i) {
            const int kc = kc0 + i;
            half8 kv = *(const half8*)(kch + gb + kc * 8);
            half8 qv = *(const half8*)(qch + gb + kc * 8);
            const int chl = t * 16 + (kc ^ (t & 15));
            *(half8*)&Ksh[chl * 8] = kv;
            *(half8*)&Qsh[chl * 8] = qv;
        }
    }
    if (tid < 64) {
        float g = lgd[(size_t)(c0 + tid) * 16 + h];
#pragma unroll
        for (int off = 1; off < 64; off <<= 1) {
            float y = __shfl_up(g, off, 64);
            if (tid >= off) g += y;
        }
        Gs[tid] = g;
        Gam[tid] = expf(g);
        Bets[tid] = bet[(size_t)(c0 + tid) * 16 + h];
    }
    __syncthreads();

    _Float16* CHb = CH + (size_t)(c * 16 + h) * 36864;
    _Float16* Ug = CHb;
    _Float16* Wtg = CHb + 8192;
    _Float16* Khg = CHb + 16384;
    _Float16* Qgg = CHb + 24576;
    _Float16* Lg = CHb + 32768;

    // MFMA: KK^T and QK^T; wave w owns i-block w
    {
        floatx4 accKK[4], accQK[4];
#pragma unroll
        for (int tt = 0; tt < 4; ++tt) { accKK[tt] = 0; accQK[tt] = 0; }
        half8 bfK[4];
#pragma unroll
        for (int ks = 0; ks < 4; ++ks) {
            const int i = wave * 16 + l15;
            const int kc = ks * 4 + quad;
            bfK[ks] = *(const half8*)&Ksh[(i * 16 + (kc ^ (i & 15))) * 8];
        }
#pragma unroll
        for (int tt = 0; tt < 4; ++tt) {
            const int t = tt * 16 + l15;
#pragma unroll
            for (int ks = 0; ks < 4; ++ks) {
                const int kc = ks * 4 + quad;
                const int chl = (t * 16 + (kc ^ (t & 15))) * 8;
                half8 afK = *(const half8*)&Ksh[chl];
                half8 afQ = *(const half8*)&Qsh[chl];
                accKK[tt] = __builtin_amdgcn_mfma_f32_16x16x32_f16(afK, bfK[ks], accKK[tt], 0, 0, 0);
                accQK[tt] = __builtin_amdgcn_mfma_f32_16x16x32_f16(afQ, bfK[ks], accQK[tt], 0, 0, 0);
            }
        }
        // form A (LDS fp32) and L (global fp16)
        const int ii = wave * 16 + l15;
        const float Gi = Gs[ii];
#pragma unroll
        for (int tt = 0; tt < 4; ++tt)
#pragma unroll
            for (int r = 0; r < 4; ++r) {
                const int t = tt * 16 + quad * 4 + r;
                const float Gt = Gs[t];
                const float ratio = (ii <= t) ? expf(Gt - Gi) : 0.f;
                if (ii < t) Amat[t * 65 + ii] = Bets[t] * ratio * accKK[tt][r];
                Lg[t * 64 + ii] = (_Float16)((ii <= t) ? ratio * accQK[tt][r] : 0.f);
            }
    }
    __syncthreads();

    // forward substitution: x = (I+A)^-1 rhs, thread = column j of [V|K]
    {
        const int j = tid;
        float x[64];
        if (j < 128) {
#pragma unroll
            for (int t = 0; t < 64; ++t)
                x[t] = Bets[t] * (float)vch[(size_t)(c0 + t) * 2048 + h * 128 + j];
        } else {
            const int k = j - 128;
#pragma unroll
            for (int t = 0; t < 64; ++t) {
                const int chl = t * 16 + ((k >> 3) ^ (t & 15));
                x[t] = Bets[t] * Gam[t] * (float)Ksh[chl * 8 + (k & 7)];
            }
        }
#pragma unroll
        for (int t = 1; t < 64; ++t) {
            float acc = 0.f;
#pragma unroll
            for (int i = 0; i < t; ++i) acc = fmaf(Amat[t * 65 + i], x[i], acc);
            x[t] -= acc;
        }
        if (j < 128) {
#pragma unroll
            for (int t = 0; t < 64; t += 4) {
                half4 w4;
                w4[0] = (_Float16)x[t]; w4[1] = (_Float16)x[t + 1];
                w4[2] = (_Float16)x[t + 2]; w4[3] = (_Float16)x[t + 3];
                *(half4*)&Wtg[j * 64 + t] = w4;
            }
        } else {
            const int k = j - 128;
#pragma unroll
            for (int t = 0; t < 64; ++t) Ug[t * 128 + k] = (_Float16)x[t];
        }
    }

    // Khat^T[k][c'] = e^{G63-Gc'} k_c'[k];  Qg[c][k] = gamma_c q_c[k]
    {
        const float g63 = Gs[63];
        const int k = tid >> 1, cb = (tid & 1) * 32;
#pragma unroll
        for (int cc = 0; cc < 32; cc += 4) {
            half4 o4;
#pragma unroll
            for (int u = 0; u < 4; ++u) {
                const int ci = cb + cc + u;
                const int chl = ci * 16 + ((k >> 3) ^ (ci & 15));
                o4[u] = (_Float16)(expf(g63 - Gs[ci]) * (float)Ksh[chl * 8 + (k & 7)]);
            }
            *(half4*)&Khg[k * 64 + cb + cc] = o4;
        }
        const int cq = tid >> 2, kb = (tid & 3) * 4;  // 4 k-chunks of 8
        const float gam = Gam[cq];
#pragma unroll
        for (int kc = 0; kc < 4; ++kc) {
            const int kcc = kb + kc;
            half8 q8 = *(const half8*)&Qsh[(cq * 16 + (kcc ^ (cq & 15))) * 8];
            half8 s8;
#pragma unroll
            for (int u = 0; u < 8; ++u) s8[u] = (_Float16)(gam * (float)q8[u]);
            *(half8*)&Qgg[cq * 128 + kcc * 8] = s8;
        }
        if (tid == 0) gamC[c * 16 + h] = Gam[63];
    }
}

// ---------------------------------------------------------------------------
// chunk_scan: sequential over 16 chunks; 32 blocks = 16 heads x 2 v-halves,
// fully independent. S fp32 in registers, fp16 copy in LDS (B-operand).
// Per chunk: delta = W - U*S; o = Qg*S + L*delta; S = gamC*S + Khat^T*delta.
// ---------------------------------------------------------------------------
__global__ __launch_bounds__(256) void chunk_scan(const _Float16* __restrict__ CH,
                                                  const float* __restrict__ gamC,
                                                  float* __restrict__ o) {
    const int h = blockIdx.x >> 1, vs = blockIdx.x & 1;
    const int tid = threadIdx.x, lane = tid & 63, wave = tid >> 6;
    const int l15 = lane & 15, quad = lane >> 4;
    const int vrow = wave * 16 + l15;          // block-local v (0..63)

    __shared__ __align__(16) _Float16 Sh[8192];  // [64 v][16 kc sw][8]
    __shared__ __align__(16) _Float16 Dt[4096];  // deltaT [64 v][8 cc sw][8]

    floatx4 Sacc[8];
#pragma unroll
    for (int kt = 0; kt < 8; ++kt) Sacc[kt] = 0;
    for (int i = tid; i < 1024; i += 256) *(int4*)&Sh[i * 8] = make_int4(0, 0, 0, 0);
    __syncthreads();

    for (int c = 0; c < 16; ++c) {
        const _Float16* CHb = CH + (size_t)(c * 16 + h) * 36864;
        const _Float16* Ug = CHb;
        const _Float16* Wtg = CHb + 8192;
        const _Float16* Khg = CHb + 16384;
        const _Float16* Qgg = CHb + 24576;
        const _Float16* Lg = CHb + 32768;

        half8 bs[4];
#pragma unroll
        for (int ks = 0; ks < 4; ++ks) {
            const int kc = ks * 4 + quad;
            bs[ks] = *(const half8*)&Sh[(vrow * 16 + (kc ^ (vrow & 15))) * 8];
        }
        // (a) X = U*S; delta = W - X -> Dt
#pragma unroll
        for (int ct = 0; ct < 4; ++ct) {
            floatx4 xa = {0.f, 0.f, 0.f, 0.f};
#pragma unroll
            for (int ks = 0; ks < 4; ++ks) {
                half8 af = *(const half8*)(Ug + (ct * 16 + l15) * 128 + ks * 32 + quad * 8);
                xa = __builtin_amdgcn_mfma_f32_16x16x32_f16(af, bs[ks], xa, 0, 0, 0);
            }
            half4 w4 = *(const half4*)(Wtg + (vs * 64 + vrow) * 64 + ct * 16 + quad * 4);
            half4 d4;
#pragma unroll
            for (int r = 0; r < 4; ++r) d4[r] = (_Float16)((float)w4[r] - xa[r]);
            const int cc = ct * 2 + (quad >> 1);
            *(half4*)&Dt[(vrow * 8 + (cc ^ (vrow & 7))) * 8 + (quad & 1) * 4] = d4;
        }
        __syncthreads();
        half8 bd[2];
#pragma unroll
        for (int cs = 0; cs < 2; ++cs) {
            const int cc = cs * 4 + quad;
            bd[cs] = *(const half8*)&Dt[(vrow * 8 + (cc ^ (vrow & 7))) * 8];
        }
        // (b) o = Qg*S + L*delta
#pragma unroll
        for (int ct = 0; ct < 4; ++ct) {
            floatx4 oa = {0.f, 0.f, 0.f, 0.f};
#pragma unroll
            for (int ks = 0; ks < 4; ++ks) {
                half8 af = *(const half8*)(Qgg + (ct * 16 + l15) * 128 + ks * 32 + quad * 8);
                oa = __builtin_amdgcn_mfma_f32_16x16x32_f16(af, bs[ks], oa, 0, 0, 0);
            }
#pragma unroll
            for (int cs = 0; cs < 2; ++cs) {
                half8 af = *(const half8*)(Lg + (ct * 16 + l15) * 64 + cs * 32 + quad * 8);
                oa = __builtin_amdgcn_mfma_f32_16x16x32_f16(af, bd[cs], oa, 0, 0, 0);
            }
            const int tg = c * 64 + ct * 16 + quad * 4;
            const int col = h * 128 + vs * 64 + vrow;
#pragma unroll
            for (int r = 0; r < 4; ++r) o[(size_t)(tg + r) * 2048 + col] = oa[r];
        }
        // (c) S = gamC*S + Khat^T * delta
        const float gC = gamC[c * 16 + h];
#pragma unroll
        for (int kt = 0; kt < 8; ++kt) {
#pragma unroll
            for (int r = 0; r < 4; ++r) Sacc[kt][r] *= gC;
#pragma unroll
            for (int cs = 0; cs < 2; ++cs) {
                half8 af = *(const half8*)(Khg + (kt * 16 + l15) * 64 + cs * 32 + quad * 8);
                Sacc[kt] = __builtin_amdgcn_mfma_f32_16x16x32_f16(af, bd[cs], Sacc[kt], 0, 0, 0);
            }
        }
        __syncthreads();
#pragma unroll
        for (int kt = 0; kt < 8; ++kt) {
            const int kc = kt * 2 + (quad >> 1);
            half4 s4;
#pragma unroll
            for (int r = 0; r < 4; ++r) s4[r] = (_Float16)Sacc[kt][r];
            *(half4*)&Sh[(vrow * 16 + (kc ^ (vrow & 15))) * 8 + (quad & 1) * 4] = s4;
        }
        __syncthreads();
    }
}

// ---------------------------------------------------------------------------
// Gated RMSNorm: xf = o * silu(z); xn = xf * rsqrt(mean(xf^2)+eps) * w
// ---------------------------------------------------------------------------
__global__ __launch_bounds__(64) void gated_norm(const float* __restrict__ o,
                                                 const float* __restrict__ qkvz,
                                                 const float* __restrict__ nw,
                                                 float* __restrict__ xn) {
    const int b = blockIdx.x;
    const int t = b >> 4;
    const int vh = b & 15;
    const int kh = vh >> 1;
    const int r = vh & 1;
    const float* op = o + (size_t)t * 2048 + vh * 128;
    const float* zp = qkvz + (size_t)t * QKVZ_N + kh * 768 + 512 + r * 128;
    const int j = threadIdx.x * 2;
    const float2 ov = *(const float2*)(op + j);
    const float2 zv = *(const float2*)(zp + j);
    const float f0 = ov.x * zv.x / (1.f + expf(-zv.x));
    const float f1 = ov.y * zv.y / (1.f + expf(-zv.y));
    float ss = f0 * f0 + f1 * f1;
#pragma unroll
    for (int m = 1; m < 64; m <<= 1) ss += __shfl_xor(ss, m, 64);
    const float rs = rsqrtf(ss * (1.f / 128.f) + 1e-6f);
    float* xp = xn + (size_t)t * 2048 + vh * 128;
    *(float2*)(xp + j) = make_float2(f0 * rs * nw[j], f1 * rs * nw[j + 1]);
}

// ---------------------------------------------------------------------------
extern "C" void kernel_launch(void* const* d_in, const int* in_sizes, int n_in,
                              void* d_out, int out_size, void* d_ws, size_t ws_size,
                              hipStream_t stream) {
    const float* hidden  = (const float*)d_in[0];
    const float* w_qkvz  = (const float*)d_in[1];
    const float* w_ba    = (const float*)d_in[2];
    const float* conv_w  = (const float*)d_in[3];
    const float* dt_bias = (const float*)d_in[4];
    const float* A_log   = (const float*)d_in[5];
    const float* norm_w  = (const float*)d_in[6];
    const float* w_out   = (const float*)d_in[7];
    float* out = (float*)d_out;

    char* w = (char*)d_ws;
    float*     qkvz = (float*)(w);                      // 25,165,824 B
    float*     ba   = (float*)(w + 25165824);           //    131,072 B
    _Float16*  qch  = (_Float16*)(w + 25296896);        //  2,097,152 B
    _Float16*  kch  = (_Float16*)(w + 27394048);        //  2,097,152 B
    _Float16*  vch  = (_Float16*)(w + 29491200);        //  4,194,304 B
    float*     lgd  = (float*)(w + 33685504);           //     65,536 B
    float*     bet  = (float*)(w + 33751040);           //     65,536 B
    float*     gamC = (float*)(w + 33816576);           //      4,096 B (pad)
    float*     o    = (float*)(w + 33820672);           //  8,388,608 B
    _Float16*  CH   = (_Float16*)(w + 42209280);        // 18,874,368 B
    float*     xn   = (float*)(w + 42209280);           // overlaps CH: CH is
                                                        // dead before xn write

    gemm_f16<<<dim3(T_LEN / 128, QKVZ_N / 128), 256, 0, stream>>>(hidden, w_qkvz, qkvz,
                                                                  T_LEN, QKVZ_N, HIDDEN);
    gemm_bt<<<dim3(1, T_LEN / 64), 256, 0, stream>>>(hidden, w_ba, ba, T_LEN, 32, HIDDEN);
    conv_silu<<<(T_LEN * 4096) / 256, 256, 0, stream>>>(qkvz, conv_w, qch, kch, vch);
    l2norm_qk<<<T_LEN * 16, 64, 0, stream>>>(qch, kch);
    gates<<<(T_LEN * 16) / 256, 256, 0, stream>>>(ba, dt_bias, A_log, lgd, bet);
    chunk_prep<<<256, 256, 0, stream>>>(qch, kch, vch, lgd, bet, CH, gamC);
    chunk_scan<<<32, 256, 0, stream>>>(CH, gamC, o);
    gated_norm<<<T_LEN * 16, 64, 0, stream>>>(o, qkvz, norm_w, xn);
    gemm_f16<<<dim3(T_LEN / 128, VAL_DIM / 128), 256, 0, stream>>>(xn, w_out, out,
                                                                   T_LEN, VAL_DIM, HIDDEN);
}

// Round 7
// 477.248 us; speedup vs baseline: 3.2709x; 1.2001x over previous
//
#include <hip/hip_runtime.h>
#include <math.h>

// ---------------- problem constants ----------------
#define T_LEN   1024
#define HIDDEN  2048
#define QKVZ_N  6144   // 2*KEY_DIM + 2*VALUE_DIM
#define VAL_DIM 2048

typedef _Float16 half8 __attribute__((ext_vector_type(8)));
typedef _Float16 half4 __attribute__((ext_vector_type(4)));
typedef _Float16 half2t __attribute__((ext_vector_type(2)));
typedef float floatx4 __attribute__((ext_vector_type(4)));

__device__ __forceinline__ float sigmoidf_(float x) { return 1.f / (1.f + expf(-x)); }

// ---------------------------------------------------------------------------
// fp16-MFMA GEMM: C[M,N] = A[M,K] * W[N,K]^T  (fp32 in/out, fp16 MFMA)
// 128x128 tile, BK=32, 4 waves 2x2, 4x4 frags of v_mfma_f32_16x16x32_f16.
// ---------------------------------------------------------------------------
__global__ __launch_bounds__(256) void gemm_f16(const float* __restrict__ A,
                                                const float* __restrict__ W,
                                                float* __restrict__ C,
                                                int M, int N, int K) {
    __shared__ __align__(16) _Float16 Ah[512 * 8];
    __shared__ __align__(16) _Float16 Bh[512 * 8];

    const int t = threadIdx.x;
    const int m0 = blockIdx.x * 128;
    const int n0 = blockIdx.y * 128;
    const int kq = t & 3;
    const int r0 = t >> 2;
    const int wave = t >> 6;
    const int lane = t & 63;
    const int wr = (wave >> 1) * 64;
    const int wc = (wave & 1) * 64;
    const int l15 = lane & 15;
    const int quad = lane >> 4;

    floatx4 acc[4][4];
#pragma unroll
    for (int i = 0; i < 4; ++i)
#pragma unroll
        for (int j = 0; j < 4; ++j) acc[i][j] = 0;

    for (int k0 = 0; k0 < K; k0 += 32) {
        float4 ag[2][2], bg[2][2];
#pragma unroll
        for (int p = 0; p < 2; ++p) {
            const int r = r0 + p * 64;
            const float4* ap = (const float4*)(A + (size_t)(m0 + r) * K + k0 + kq * 8);
            const float4* bp = (const float4*)(W + (size_t)(n0 + r) * K + k0 + kq * 8);
            ag[p][0] = ap[0]; ag[p][1] = ap[1];
            bg[p][0] = bp[0]; bg[p][1] = bp[1];
        }
        __syncthreads();
#pragma unroll
        for (int p = 0; p < 2; ++p) {
            const int r = r0 + p * 64;
            const int chunk = r * 4 + (kq ^ (r & 3));
            half8 ha, hb;
            ha[0] = (_Float16)ag[p][0].x; ha[1] = (_Float16)ag[p][0].y;
            ha[2] = (_Float16)ag[p][0].z; ha[3] = (_Float16)ag[p][0].w;
            ha[4] = (_Float16)ag[p][1].x; ha[5] = (_Float16)ag[p][1].y;
            ha[6] = (_Float16)ag[p][1].z; ha[7] = (_Float16)ag[p][1].w;
            hb[0] = (_Float16)bg[p][0].x; hb[1] = (_Float16)bg[p][0].y;
            hb[2] = (_Float16)bg[p][0].z; hb[3] = (_Float16)bg[p][0].w;
            hb[4] = (_Float16)bg[p][1].x; hb[5] = (_Float16)bg[p][1].y;
            hb[6] = (_Float16)bg[p][1].z; hb[7] = (_Float16)bg[p][1].w;
            *(half8*)&Ah[chunk * 8] = ha;
            *(half8*)&Bh[chunk * 8] = hb;
        }
        __syncthreads();
        half8 af[4], bf[4];
#pragma unroll
        for (int mt = 0; mt < 4; ++mt) {
            const int m = wr + mt * 16 + l15;
            af[mt] = *(const half8*)&Ah[(m * 4 + (quad ^ (m & 3))) * 8];
        }
#pragma unroll
        for (int nt = 0; nt < 4; ++nt) {
            const int n = wc + nt * 16 + l15;
            bf[nt] = *(const half8*)&Bh[(n * 4 + (quad ^ (n & 3))) * 8];
        }
#pragma unroll
        for (int mt = 0; mt < 4; ++mt)
#pragma unroll
            for (int nt = 0; nt < 4; ++nt)
                acc[mt][nt] = __builtin_amdgcn_mfma_f32_16x16x32_f16(
                    af[mt], bf[nt], acc[mt][nt], 0, 0, 0);
    }
#pragma unroll
    for (int mt = 0; mt < 4; ++mt)
#pragma unroll
        for (int nt = 0; nt < 4; ++nt) {
            const int c = n0 + wc + nt * 16 + l15;
#pragma unroll
            for (int reg = 0; reg < 4; ++reg) {
                const int r = m0 + wr + mt * 16 + quad * 4 + reg;
                C[(size_t)r * N + c] = acc[mt][nt][reg];
            }
        }
}

// ---------------------------------------------------------------------------
// fp32 GEMM for the tiny ba projection (N=32)
// ---------------------------------------------------------------------------
__global__ __launch_bounds__(256) void gemm_bt(const float* __restrict__ A,
                                               const float* __restrict__ B,
                                               float* __restrict__ C,
                                               int M, int N, int K) {
    __shared__ float As[16][68];
    __shared__ float Bs[16][68];
    const int tid = threadIdx.x;
    const int m0 = blockIdx.y * 64;
    const int n0 = blockIdx.x * 64;
    const int tx = tid & 15;
    const int ty = tid >> 4;
    const int lr = tid >> 2;
    const int lk = (tid & 3) << 2;

    float acc[4][4];
#pragma unroll
    for (int i = 0; i < 4; ++i)
#pragma unroll
        for (int j = 0; j < 4; ++j) acc[i][j] = 0.f;

    for (int k0 = 0; k0 < K; k0 += 16) {
        float4 av = *(const float4*)(A + (size_t)(m0 + lr) * K + k0 + lk);
        float4 bv = make_float4(0.f, 0.f, 0.f, 0.f);
        if (n0 + lr < N) bv = *(const float4*)(B + (size_t)(n0 + lr) * K + k0 + lk);
        __syncthreads();
        As[lk + 0][lr] = av.x; As[lk + 1][lr] = av.y; As[lk + 2][lr] = av.z; As[lk + 3][lr] = av.w;
        Bs[lk + 0][lr] = bv.x; Bs[lk + 1][lr] = bv.y; Bs[lk + 2][lr] = bv.z; Bs[lk + 3][lr] = bv.w;
        __syncthreads();
#pragma unroll
        for (int kk = 0; kk < 16; ++kk) {
            float4 a4 = *(const float4*)&As[kk][ty << 2];
            float4 b4 = *(const float4*)&Bs[kk][tx << 2];
            const float ar[4] = {a4.x, a4.y, a4.z, a4.w};
            const float br[4] = {b4.x, b4.y, b4.z, b4.w};
#pragma unroll
            for (int i = 0; i < 4; ++i)
#pragma unroll
                for (int j = 0; j < 4; ++j) acc[i][j] = fmaf(ar[i], br[j], acc[i][j]);
        }
    }
#pragma unroll
    for (int i = 0; i < 4; ++i) {
        const int row = m0 + (ty << 2) + i;
        const int col = n0 + (tx << 2);
#pragma unroll
        for (int j = 0; j < 4; ++j)
            if (col + j < N) C[(size_t)row * N + col + j] = acc[i][j];
    }
}

// ---------------------------------------------------------------------------
// Depthwise causal conv1d (K=4) + SiLU; outputs fp16 q/k/v.
// qkvz row layout per k-head block of 768: [q 128 | k 128 | v 256 | z 256]
// ---------------------------------------------------------------------------
__global__ __launch_bounds__(256) void conv_silu(const float* __restrict__ qkvz,
                                                 const float* __restrict__ conv_w,
                                                 _Float16* __restrict__ qc,
                                                 _Float16* __restrict__ kc,
                                                 _Float16* __restrict__ vc) {
    const int idx = blockIdx.x * 256 + threadIdx.x;
    const int t = idx >> 12;
    const int c = idx & 4095;
    int col;
    _Float16* dst;
    if (c < 1024) {
        col = ((c >> 7) * 768) + (c & 127);
        dst = qc + t * 1024 + c;
    } else if (c < 2048) {
        const int cc = c - 1024;
        col = ((cc >> 7) * 768) + 128 + (cc & 127);
        dst = kc + t * 1024 + cc;
    } else {
        const int cc = c - 2048;
        col = ((cc >> 8) * 768) + 256 + (cc & 255);
        dst = vc + t * 2048 + cc;
    }
    const float w0 = conv_w[c * 4 + 0];
    const float w1 = conv_w[c * 4 + 1];
    const float w2 = conv_w[c * 4 + 2];
    const float w3 = conv_w[c * 4 + 3];
    float acc = qkvz[(size_t)t * QKVZ_N + col] * w3;
    if (t >= 1) acc = fmaf(qkvz[(size_t)(t - 1) * QKVZ_N + col], w2, acc);
    if (t >= 2) acc = fmaf(qkvz[(size_t)(t - 2) * QKVZ_N + col], w1, acc);
    if (t >= 3) acc = fmaf(qkvz[(size_t)(t - 3) * QKVZ_N + col], w0, acc);
    *dst = (_Float16)(acc * sigmoidf_(acc));
}

// ---------------------------------------------------------------------------
// L2 normalize q and k per (t, k-head) on fp16 buffers; fold 128^-0.5 into q.
// ---------------------------------------------------------------------------
__global__ __launch_bounds__(64) void l2norm_qk(_Float16* __restrict__ qc,
                                                _Float16* __restrict__ kc) {
    const int b = blockIdx.x;
    const int t = b >> 4;
    const int hh = b & 15;
    _Float16* p;
    float extra;
    if (hh < 8) { p = qc + t * 1024 + hh * 128; extra = 0.08838834764831845f; }
    else        { p = kc + t * 1024 + (hh - 8) * 128; extra = 1.f; }
    const int j = threadIdx.x * 2;
    half2t x = *(const half2t*)(p + j);
    const float x0 = (float)x[0], x1 = (float)x[1];
    float ss = x0 * x0 + x1 * x1;
#pragma unroll
    for (int m = 1; m < 64; m <<= 1) ss += __shfl_xor(ss, m, 64);
    const float r = rsqrtf(ss + 1e-6f) * extra;
    half2t y; y[0] = (_Float16)(x0 * r); y[1] = (_Float16)(x1 * r);
    *(half2t*)(p + j) = y;
}

// ---------------------------------------------------------------------------
// Gates: beta = sigmoid(b); lgd = log-decay = -exp(A_log)*softplus(a+dt_bias)
// ---------------------------------------------------------------------------
__global__ __launch_bounds__(256) void gates(const float* __restrict__ ba,
                                             const float* __restrict__ dt_bias,
                                             const float* __restrict__ A_log,
                                             float* __restrict__ lgd,
                                             float* __restrict__ bet) {
    const int i = blockIdx.x * 256 + threadIdx.x;
    const int t = i >> 4;
    const int vh = i & 15;
    const int kh = vh >> 1;
    const int r = vh & 1;
    const float b = ba[t * 32 + kh * 4 + r];
    const float a = ba[t * 32 + kh * 4 + 2 + r];
    bet[i] = 1.f / (1.f + expf(-b));
    const float x = a + dt_bias[vh];
    const float sp = (x > 0.f) ? (x + log1pf(expf(-x))) : log1pf(expf(x));
    lgd[i] = -expf(A_log[vh]) * sp;
}

// ---------------------------------------------------------------------------
// chunk_prep (unchanged from R6): per (chunk c, v-head h), fully parallel.
// Outputs fp16 blob per chunk-head: U[64x128] Wt[128x64] Kh[128x64]
//   Qg[64x128] L[64x64]  (36864 halves)
// ---------------------------------------------------------------------------
__global__ __launch_bounds__(256) void chunk_prep(
    const _Float16* __restrict__ qch, const _Float16* __restrict__ kch,
    const _Float16* __restrict__ vch, const float* __restrict__ lgd,
    const float* __restrict__ bet, _Float16* __restrict__ CH,
    float* __restrict__ gamC) {
    const int blk = blockIdx.x;
    const int c = blk >> 4, h = blk & 15, kh = h >> 1;
    const int c0 = c * 64;
    const int tid = threadIdx.x, lane = tid & 63, wave = tid >> 6;
    const int l15 = lane & 15, quad = lane >> 4;

    __shared__ __align__(16) _Float16 Ksh[8192];  // [t][kc sw][8]
    __shared__ __align__(16) _Float16 Qsh[8192];
    __shared__ float Amat[64 * 65];
    __shared__ float Gs[64], Bets[64], Gam[64];

    {
        const int t = tid >> 2, kc0 = (tid & 3) * 4;
        const size_t gb = (size_t)(c0 + t) * 1024 + kh * 128;
#pragma unroll
        for (int i = 0; i < 4; ++i) {
            const int kc = kc0 + i;
            half8 kv = *(const half8*)(kch + gb + kc * 8);
            half8 qv = *(const half8*)(qch + gb + kc * 8);
            const int chl = t * 16 + (kc ^ (t & 15));
            *(half8*)&Ksh[chl * 8] = kv;
            *(half8*)&Qsh[chl * 8] = qv;
        }
    }
    if (tid < 64) {
        float g = lgd[(size_t)(c0 + tid) * 16 + h];
#pragma unroll
        for (int off = 1; off < 64; off <<= 1) {
            float y = __shfl_up(g, off, 64);
            if (tid >= off) g += y;
        }
        Gs[tid] = g;
        Gam[tid] = expf(g);
        Bets[tid] = bet[(size_t)(c0 + tid) * 16 + h];
    }
    __syncthreads();

    _Float16* CHb = CH + (size_t)(c * 16 + h) * 36864;
    _Float16* Ug = CHb;
    _Float16* Wtg = CHb + 8192;
    _Float16* Khg = CHb + 16384;
    _Float16* Qgg = CHb + 24576;
    _Float16* Lg = CHb + 32768;

    {
        floatx4 accKK[4], accQK[4];
#pragma unroll
        for (int tt = 0; tt < 4; ++tt) { accKK[tt] = 0; accQK[tt] = 0; }
        half8 bfK[4];
#pragma unroll
        for (int ks = 0; ks < 4; ++ks) {
            const int i = wave * 16 + l15;
            const int kc = ks * 4 + quad;
            bfK[ks] = *(const half8*)&Ksh[(i * 16 + (kc ^ (i & 15))) * 8];
        }
#pragma unroll
        for (int tt = 0; tt < 4; ++tt) {
            const int t = tt * 16 + l15;
#pragma unroll
            for (int ks = 0; ks < 4; ++ks) {
                const int kc = ks * 4 + quad;
                const int chl = (t * 16 + (kc ^ (t & 15))) * 8;
                half8 afK = *(const half8*)&Ksh[chl];
                half8 afQ = *(const half8*)&Qsh[chl];
                accKK[tt] = __builtin_amdgcn_mfma_f32_16x16x32_f16(afK, bfK[ks], accKK[tt], 0, 0, 0);
                accQK[tt] = __builtin_amdgcn_mfma_f32_16x16x32_f16(afQ, bfK[ks], accQK[tt], 0, 0, 0);
            }
        }
        const int ii = wave * 16 + l15;
        const float Gi = Gs[ii];
#pragma unroll
        for (int tt = 0; tt < 4; ++tt)
#pragma unroll
            for (int r = 0; r < 4; ++r) {
                const int t = tt * 16 + quad * 4 + r;
                const float Gt = Gs[t];
                const float ratio = (ii <= t) ? expf(Gt - Gi) : 0.f;
                if (ii < t) Amat[t * 65 + ii] = Bets[t] * ratio * accKK[tt][r];
                Lg[t * 64 + ii] = (_Float16)((ii <= t) ? ratio * accQK[tt][r] : 0.f);
            }
    }
    __syncthreads();

    {
        const int j = tid;
        float x[64];
        if (j < 128) {
#pragma unroll
            for (int t = 0; t < 64; ++t)
                x[t] = Bets[t] * (float)vch[(size_t)(c0 + t) * 2048 + h * 128 + j];
        } else {
            const int k = j - 128;
#pragma unroll
            for (int t = 0; t < 64; ++t) {
                const int chl = t * 16 + ((k >> 3) ^ (t & 15));
                x[t] = Bets[t] * Gam[t] * (float)Ksh[chl * 8 + (k & 7)];
            }
        }
#pragma unroll
        for (int t = 1; t < 64; ++t) {
            float acc = 0.f;
#pragma unroll
            for (int i = 0; i < t; ++i) acc = fmaf(Amat[t * 65 + i], x[i], acc);
            x[t] -= acc;
        }
        if (j < 128) {
#pragma unroll
            for (int t = 0; t < 64; t += 4) {
                half4 w4;
                w4[0] = (_Float16)x[t]; w4[1] = (_Float16)x[t + 1];
                w4[2] = (_Float16)x[t + 2]; w4[3] = (_Float16)x[t + 3];
                *(half4*)&Wtg[j * 64 + t] = w4;
            }
        } else {
            const int k = j - 128;
#pragma unroll
            for (int t = 0; t < 64; ++t) Ug[t * 128 + k] = (_Float16)x[t];
        }
    }

    {
        const float g63 = Gs[63];
        const int k = tid >> 1, cb = (tid & 1) * 32;
#pragma unroll
        for (int cc = 0; cc < 32; cc += 4) {
            half4 o4;
#pragma unroll
            for (int u = 0; u < 4; ++u) {
                const int ci = cb + cc + u;
                const int chl = ci * 16 + ((k >> 3) ^ (ci & 15));
                o4[u] = (_Float16)(expf(g63 - Gs[ci]) * (float)Ksh[chl * 8 + (k & 7)]);
            }
            *(half4*)&Khg[k * 64 + cb + cc] = o4;
        }
        const int cq = tid >> 2, kb = (tid & 3) * 4;
        const float gam = Gam[cq];
#pragma unroll
        for (int kc = 0; kc < 4; ++kc) {
            const int kcc = kb + kc;
            half8 q8 = *(const half8*)&Qsh[(cq * 16 + (kcc ^ (cq & 15))) * 8];
            half8 s8;
#pragma unroll
            for (int u = 0; u < 8; ++u) s8[u] = (_Float16)(gam * (float)q8[u]);
            *(half8*)&Qgg[cq * 128 + kcc * 8] = s8;
        }
        if (tid == 0) gamC[c * 16 + h] = Gam[63];
    }
}

// ---------------------------------------------------------------------------
// chunk_scan v2: sequential over 16 chunks; 32 blocks = 16 heads x 2 v-halves.
// Per chunk, the 64 KB operand blob is cooperatively STAGED INTO LDS first
// (16 independent int4 loads/thread, one latency exposure) — R6 read A-frags
// straight from global and serialized ~72 L2 latencies per wave per chunk.
// Rows padded to 17/9 16B-chunks (stride 272/144 B -> worst 2-way = free).
// Sh and Dt are wave-private by v-row -> no mid-chunk barrier needed.
// Per chunk: delta = W - U*S; o = Qg*S + L*delta; S = gamC*S + Khat^T*delta.
// ---------------------------------------------------------------------------
__global__ __launch_bounds__(256) void chunk_scan(const _Float16* __restrict__ CH,
                                                  const float* __restrict__ gamC,
                                                  float* __restrict__ o) {
    const int h = blockIdx.x >> 1, vs = blockIdx.x & 1;
    const int tid = threadIdx.x, lane = tid & 63, wave = tid >> 6;
    const int l15 = lane & 15, quad = lane >> 4;
    const int vrow = wave * 16 + l15;          // block-local v (0..63)

    __shared__ __align__(16) _Float16 Sh[8192];   // [64 v][16 kc sw][8]
    __shared__ __align__(16) _Float16 Dt[4096];   // deltaT [64 v][8 cc sw][8]
    __shared__ __align__(16) _Float16 LUg[8704];  // 64 x (16+1 pad) chunks
    __shared__ __align__(16) _Float16 LWt[4608];  // 64 x (8+1)
    __shared__ __align__(16) _Float16 LKh[9216];  // 128 x (8+1)
    __shared__ __align__(16) _Float16 LQg[8704];  // 64 x (16+1)
    __shared__ __align__(16) _Float16 LLg[4608];  // 64 x (8+1)

    floatx4 Sacc[8];
#pragma unroll
    for (int kt = 0; kt < 8; ++kt) Sacc[kt] = 0;
    for (int i = tid; i < 1024; i += 256) *(int4*)&Sh[i * 8] = make_int4(0, 0, 0, 0);
    __syncthreads();

    for (int c = 0; c < 16; ++c) {
        const _Float16* CHb = CH + (size_t)(c * 16 + h) * 36864;
        // ---- cooperative stage: 64 KB -> LDS, 16 int4 per thread ----
        {
            const int4* src = (const int4*)CHb;                    // Ug 64x16
#pragma unroll
            for (int i = 0; i < 4; ++i) {
                const int idx = tid + i * 256;
                *(int4*)&LUg[((idx >> 4) * 17 + (idx & 15)) * 8] = src[idx];
            }
        }
        {
            const int4* src = (const int4*)(CHb + 8192 + vs * 4096);  // Wt 64x8
#pragma unroll
            for (int i = 0; i < 2; ++i) {
                const int idx = tid + i * 256;
                *(int4*)&LWt[((idx >> 3) * 9 + (idx & 7)) * 8] = src[idx];
            }
        }
        {
            const int4* src = (const int4*)(CHb + 16384);          // Khg 128x8
#pragma unroll
            for (int i = 0; i < 4; ++i) {
                const int idx = tid + i * 256;
                *(int4*)&LKh[((idx >> 3) * 9 + (idx & 7)) * 8] = src[idx];
            }
        }
        {
            const int4* src = (const int4*)(CHb + 24576);          // Qgg 64x16
#pragma unroll
            for (int i = 0; i < 4; ++i) {
                const int idx = tid + i * 256;
                *(int4*)&LQg[((idx >> 4) * 17 + (idx & 15)) * 8] = src[idx];
            }
        }
        {
            const int4* src = (const int4*)(CHb + 32768);          // Lg 64x8
#pragma unroll
            for (int i = 0; i < 2; ++i) {
                const int idx = tid + i * 256;
                *(int4*)&LLg[((idx >> 3) * 9 + (idx & 7)) * 8] = src[idx];
            }
        }
        __syncthreads();

        // ---- compute ----
        half8 bs[4];
#pragma unroll
        for (int ks = 0; ks < 4; ++ks) {
            const int kc = ks * 4 + quad;
            bs[ks] = *(const half8*)&Sh[(vrow * 16 + (kc ^ (vrow & 15))) * 8];
        }
        // (a) X = U*S; delta = W - X -> Dt (wave-private rows)
#pragma unroll
        for (int ct = 0; ct < 4; ++ct) {
            floatx4 xa = {0.f, 0.f, 0.f, 0.f};
#pragma unroll
            for (int ks = 0; ks < 4; ++ks) {
                half8 af = *(const half8*)&LUg[((ct * 16 + l15) * 17 + ks * 4 + quad) * 8];
                xa = __builtin_amdgcn_mfma_f32_16x16x32_f16(af, bs[ks], xa, 0, 0, 0);
            }
            half4 w4 = *(const half4*)&LWt[(vrow * 9 + ct * 2 + (quad >> 1)) * 8 + (quad & 1) * 4];
            half4 d4;
#pragma unroll
            for (int r = 0; r < 4; ++r) d4[r] = (_Float16)((float)w4[r] - xa[r]);
            const int cc = ct * 2 + (quad >> 1);
            *(half4*)&Dt[(vrow * 8 + (cc ^ (vrow & 7))) * 8 + (quad & 1) * 4] = d4;
        }
        half8 bd[2];
#pragma unroll
        for (int cs = 0; cs < 2; ++cs) {
            const int cc = cs * 4 + quad;
            bd[cs] = *(const half8*)&Dt[(vrow * 8 + (cc ^ (vrow & 7))) * 8];
        }
        // (b) o = Qg*S + L*delta
#pragma unroll
        for (int ct = 0; ct < 4; ++ct) {
            floatx4 oa = {0.f, 0.f, 0.f, 0.f};
#pragma unroll
            for (int ks = 0; ks < 4; ++ks) {
                half8 af = *(const half8*)&LQg[((ct * 16 + l15) * 17 + ks * 4 + quad) * 8];
                oa = __builtin_amdgcn_mfma_f32_16x16x32_f16(af, bs[ks], oa, 0, 0, 0);
            }
#pragma unroll
            for (int cs = 0; cs < 2; ++cs) {
                half8 af = *(const half8*)&LLg[((ct * 16 + l15) * 9 + cs * 4 + quad) * 8];
                oa = __builtin_amdgcn_mfma_f32_16x16x32_f16(af, bd[cs], oa, 0, 0, 0);
            }
            const int tg = c * 64 + ct * 16 + quad * 4;
            const int col = h * 128 + vs * 64 + vrow;
#pragma unroll
            for (int r = 0; r < 4; ++r) o[(size_t)(tg + r) * 2048 + col] = oa[r];
        }
        // (c) S = gamC*S + Khat^T * delta
        const float gC = gamC[c * 16 + h];
#pragma unroll
        for (int kt = 0; kt < 8; ++kt) {
#pragma unroll
            for (int r = 0; r < 4; ++r) Sacc[kt][r] *= gC;
#pragma unroll
            for (int cs = 0; cs < 2; ++cs) {
                half8 af = *(const half8*)&LKh[((kt * 16 + l15) * 9 + cs * 4 + quad) * 8];
                Sacc[kt] = __builtin_amdgcn_mfma_f32_16x16x32_f16(af, bd[cs], Sacc[kt], 0, 0, 0);
            }
        }
        // S writeback (wave-private rows, no barrier needed before reads)
#pragma unroll
        for (int kt = 0; kt < 8; ++kt) {
            const int kc = kt * 2 + (quad >> 1);
            half4 s4;
#pragma unroll
            for (int r = 0; r < 4; ++r) s4[r] = (_Float16)Sacc[kt][r];
            *(half4*)&Sh[(vrow * 16 + (kc ^ (vrow & 15))) * 8 + (quad & 1) * 4] = s4;
        }
        __syncthreads();  // all CH reads done before next chunk's stage
    }
}

// ---------------------------------------------------------------------------
// Gated RMSNorm: xf = o * silu(z); xn = xf * rsqrt(mean(xf^2)+eps) * w
// ---------------------------------------------------------------------------
__global__ __launch_bounds__(64) void gated_norm(const float* __restrict__ o,
                                                 const float* __restrict__ qkvz,
                                                 const float* __restrict__ nw,
                                                 float* __restrict__ xn) {
    const int b = blockIdx.x;
    const int t = b >> 4;
    const int vh = b & 15;
    const int kh = vh >> 1;
    const int r = vh & 1;
    const float* op = o + (size_t)t * 2048 + vh * 128;
    const float* zp = qkvz + (size_t)t * QKVZ_N + kh * 768 + 512 + r * 128;
    const int j = threadIdx.x * 2;
    const float2 ov = *(const float2*)(op + j);
    const float2 zv = *(const float2*)(zp + j);
    const float f0 = ov.x * zv.x / (1.f + expf(-zv.x));
    const float f1 = ov.y * zv.y / (1.f + expf(-zv.y));
    float ss = f0 * f0 + f1 * f1;
#pragma unroll
    for (int m = 1; m < 64; m <<= 1) ss += __shfl_xor(ss, m, 64);
    const float rs = rsqrtf(ss * (1.f / 128.f) + 1e-6f);
    float* xp = xn + (size_t)t * 2048 + vh * 128;
    *(float2*)(xp + j) = make_float2(f0 * rs * nw[j], f1 * rs * nw[j + 1]);
}

// ---------------------------------------------------------------------------
extern "C" void kernel_launch(void* const* d_in, const int* in_sizes, int n_in,
                              void* d_out, int out_size, void* d_ws, size_t ws_size,
                              hipStream_t stream) {
    const float* hidden  = (const float*)d_in[0];
    const float* w_qkvz  = (const float*)d_in[1];
    const float* w_ba    = (const float*)d_in[2];
    const float* conv_w  = (const float*)d_in[3];
    const float* dt_bias = (const float*)d_in[4];
    const float* A_log   = (const float*)d_in[5];
    const float* norm_w  = (const float*)d_in[6];
    const float* w_out   = (const float*)d_in[7];
    float* out = (float*)d_out;

    char* w = (char*)d_ws;
    float*     qkvz = (float*)(w);                      // 25,165,824 B
    float*     ba   = (float*)(w + 25165824);           //    131,072 B
    _Float16*  qch  = (_Float16*)(w + 25296896);        //  2,097,152 B
    _Float16*  kch  = (_Float16*)(w + 27394048);        //  2,097,152 B
    _Float16*  vch  = (_Float16*)(w + 29491200);        //  4,194,304 B
    float*     lgd  = (float*)(w + 33685504);           //     65,536 B
    float*     bet  = (float*)(w + 33751040);           //     65,536 B
    float*     gamC = (float*)(w + 33816576);           //      4,096 B (pad)
    float*     o    = (float*)(w + 33820672);           //  8,388,608 B
    _Float16*  CH   = (_Float16*)(w + 42209280);        // 18,874,368 B
    float*     xn   = (float*)(w + 42209280);           // overlaps CH: CH is
                                                        // dead before xn write

    gemm_f16<<<dim3(T_LEN / 128, QKVZ_N / 128), 256, 0, stream>>>(hidden, w_qkvz, qkvz,
                                                                  T_LEN, QKVZ_N, HIDDEN);
    gemm_bt<<<dim3(1, T_LEN / 64), 256, 0, stream>>>(hidden, w_ba, ba, T_LEN, 32, HIDDEN);
    conv_silu<<<(T_LEN * 4096) / 256, 256, 0, stream>>>(qkvz, conv_w, qch, kch, vch);
    l2norm_qk<<<T_LEN * 16, 64, 0, stream>>>(qch, kch);
    gates<<<(T_LEN * 16) / 256, 256, 0, stream>>>(ba, dt_bias, A_log, lgd, bet);
    chunk_prep<<<256, 256, 0, stream>>>(qch, kch, vch, lgd, bet, CH, gamC);
    chunk_scan<<<32, 256, 0, stream>>>(CH, gamC, o);
    gated_norm<<<T_LEN * 16, 64, 0, stream>>>(o, qkvz, norm_w, xn);
    gemm_f16<<<dim3(T_LEN / 128, VAL_DIM / 128), 256, 0, stream>>>(xn, w_out, out,
                                                                   T_LEN, VAL_DIM, HIDDEN);
}

// Round 8
// 385.678 us; speedup vs baseline: 4.0475x; 1.2374x over previous
//
#include <hip/hip_runtime.h>
#include <math.h>

// ---------------- problem constants ----------------
#define T_LEN   1024
#define HIDDEN  2048
#define QKVZ_N  6144   // 2*KEY_DIM + 2*VALUE_DIM
#define VAL_DIM 2048

typedef _Float16 half8 __attribute__((ext_vector_type(8)));
typedef _Float16 half4 __attribute__((ext_vector_type(4)));
typedef _Float16 half2t __attribute__((ext_vector_type(2)));
typedef float floatx4 __attribute__((ext_vector_type(4)));

__device__ __forceinline__ float sigmoidf_(float x) { return 1.f / (1.f + expf(-x)); }

// ---------------------------------------------------------------------------
// fp16-MFMA GEMM: C[M,N] = A[M,K] * W[N,K]^T  (fp32 in/out, fp16 MFMA)
// 128x128 tile, BK=32, 4 waves 2x2, 4x4 frags of v_mfma_f32_16x16x32_f16.
// ---------------------------------------------------------------------------
__global__ __launch_bounds__(256) void gemm_f16(const float* __restrict__ A,
                                                const float* __restrict__ W,
                                                float* __restrict__ C,
                                                int M, int N, int K) {
    __shared__ __align__(16) _Float16 Ah[512 * 8];
    __shared__ __align__(16) _Float16 Bh[512 * 8];

    const int t = threadIdx.x;
    const int m0 = blockIdx.x * 128;
    const int n0 = blockIdx.y * 128;
    const int kq = t & 3;
    const int r0 = t >> 2;
    const int wave = t >> 6;
    const int lane = t & 63;
    const int wr = (wave >> 1) * 64;
    const int wc = (wave & 1) * 64;
    const int l15 = lane & 15;
    const int quad = lane >> 4;

    floatx4 acc[4][4];
#pragma unroll
    for (int i = 0; i < 4; ++i)
#pragma unroll
        for (int j = 0; j < 4; ++j) acc[i][j] = 0;

    for (int k0 = 0; k0 < K; k0 += 32) {
        float4 ag[2][2], bg[2][2];
#pragma unroll
        for (int p = 0; p < 2; ++p) {
            const int r = r0 + p * 64;
            const float4* ap = (const float4*)(A + (size_t)(m0 + r) * K + k0 + kq * 8);
            const float4* bp = (const float4*)(W + (size_t)(n0 + r) * K + k0 + kq * 8);
            ag[p][0] = ap[0]; ag[p][1] = ap[1];
            bg[p][0] = bp[0]; bg[p][1] = bp[1];
        }
        __syncthreads();
#pragma unroll
        for (int p = 0; p < 2; ++p) {
            const int r = r0 + p * 64;
            const int chunk = r * 4 + (kq ^ (r & 3));
            half8 ha, hb;
            ha[0] = (_Float16)ag[p][0].x; ha[1] = (_Float16)ag[p][0].y;
            ha[2] = (_Float16)ag[p][0].z; ha[3] = (_Float16)ag[p][0].w;
            ha[4] = (_Float16)ag[p][1].x; ha[5] = (_Float16)ag[p][1].y;
            ha[6] = (_Float16)ag[p][1].z; ha[7] = (_Float16)ag[p][1].w;
            hb[0] = (_Float16)bg[p][0].x; hb[1] = (_Float16)bg[p][0].y;
            hb[2] = (_Float16)bg[p][0].z; hb[3] = (_Float16)bg[p][0].w;
            hb[4] = (_Float16)bg[p][1].x; hb[5] = (_Float16)bg[p][1].y;
            hb[6] = (_Float16)bg[p][1].z; hb[7] = (_Float16)bg[p][1].w;
            *(half8*)&Ah[chunk * 8] = ha;
            *(half8*)&Bh[chunk * 8] = hb;
        }
        __syncthreads();
        half8 af[4], bf[4];
#pragma unroll
        for (int mt = 0; mt < 4; ++mt) {
            const int m = wr + mt * 16 + l15;
            af[mt] = *(const half8*)&Ah[(m * 4 + (quad ^ (m & 3))) * 8];
        }
#pragma unroll
        for (int nt = 0; nt < 4; ++nt) {
            const int n = wc + nt * 16 + l15;
            bf[nt] = *(const half8*)&Bh[(n * 4 + (quad ^ (n & 3))) * 8];
        }
#pragma unroll
        for (int mt = 0; mt < 4; ++mt)
#pragma unroll
            for (int nt = 0; nt < 4; ++nt)
                acc[mt][nt] = __builtin_amdgcn_mfma_f32_16x16x32_f16(
                    af[mt], bf[nt], acc[mt][nt], 0, 0, 0);
    }
#pragma unroll
    for (int mt = 0; mt < 4; ++mt)
#pragma unroll
        for (int nt = 0; nt < 4; ++nt) {
            const int c = n0 + wc + nt * 16 + l15;
#pragma unroll
            for (int reg = 0; reg < 4; ++reg) {
                const int r = m0 + wr + mt * 16 + quad * 4 + reg;
                C[(size_t)r * N + c] = acc[mt][nt][reg];
            }
        }
}

// ---------------------------------------------------------------------------
// ba projection: C[1024,32] = A[1024,2048] * W[32,2048]^T.
// One block per row m, 256 threads = 8 n-groups x 32 k-lanes, no LDS/barriers
// (the 64x64-tile GEMM ran this with 16 blocks -> latency-bound 114 us).
// A-row fragment kept in regs across the 4 n-iterations; W reads coalesced;
// 5 shfl_xor reduce over k-lanes.
// ---------------------------------------------------------------------------
__global__ __launch_bounds__(256) void gemm_ba(const float* __restrict__ A,
                                               const float* __restrict__ W,
                                               float* __restrict__ C) {
    const int m = blockIdx.x;
    const int tid = threadIdx.x;
    const int kl = tid & 31;   // k lane
    const int ng = tid >> 5;   // n group 0..7
    const float* Arow = A + (size_t)m * 2048;

    float4 a4[16];
#pragma unroll
    for (int j = 0; j < 16; ++j)
        a4[j] = *(const float4*)(Arow + j * 128 + kl * 4);

#pragma unroll
    for (int nn = 0; nn < 4; ++nn) {
        const int n = nn * 8 + ng;
        const float* Wrow = W + (size_t)n * 2048;
        float acc = 0.f;
#pragma unroll
        for (int j = 0; j < 16; ++j) {
            const float4 w4 = *(const float4*)(Wrow + j * 128 + kl * 4);
            acc = fmaf(a4[j].x, w4.x, acc);
            acc = fmaf(a4[j].y, w4.y, acc);
            acc = fmaf(a4[j].z, w4.z, acc);
            acc = fmaf(a4[j].w, w4.w, acc);
        }
        acc += __shfl_xor(acc, 1, 64);
        acc += __shfl_xor(acc, 2, 64);
        acc += __shfl_xor(acc, 4, 64);
        acc += __shfl_xor(acc, 8, 64);
        acc += __shfl_xor(acc, 16, 64);
        if (kl == 0) C[m * 32 + n] = acc;
    }
}

// ---------------------------------------------------------------------------
// Depthwise causal conv1d (K=4) + SiLU; outputs fp16 q/k/v.
// qkvz row layout per k-head block of 768: [q 128 | k 128 | v 256 | z 256]
// ---------------------------------------------------------------------------
__global__ __launch_bounds__(256) void conv_silu(const float* __restrict__ qkvz,
                                                 const float* __restrict__ conv_w,
                                                 _Float16* __restrict__ qc,
                                                 _Float16* __restrict__ kc,
                                                 _Float16* __restrict__ vc) {
    const int idx = blockIdx.x * 256 + threadIdx.x;
    const int t = idx >> 12;
    const int c = idx & 4095;
    int col;
    _Float16* dst;
    if (c < 1024) {
        col = ((c >> 7) * 768) + (c & 127);
        dst = qc + t * 1024 + c;
    } else if (c < 2048) {
        const int cc = c - 1024;
        col = ((cc >> 7) * 768) + 128 + (cc & 127);
        dst = kc + t * 1024 + cc;
    } else {
        const int cc = c - 2048;
        col = ((cc >> 8) * 768) + 256 + (cc & 255);
        dst = vc + t * 2048 + cc;
    }
    const float w0 = conv_w[c * 4 + 0];
    const float w1 = conv_w[c * 4 + 1];
    const float w2 = conv_w[c * 4 + 2];
    const float w3 = conv_w[c * 4 + 3];
    float acc = qkvz[(size_t)t * QKVZ_N + col] * w3;
    if (t >= 1) acc = fmaf(qkvz[(size_t)(t - 1) * QKVZ_N + col], w2, acc);
    if (t >= 2) acc = fmaf(qkvz[(size_t)(t - 2) * QKVZ_N + col], w1, acc);
    if (t >= 3) acc = fmaf(qkvz[(size_t)(t - 3) * QKVZ_N + col], w0, acc);
    *dst = (_Float16)(acc * sigmoidf_(acc));
}

// ---------------------------------------------------------------------------
// L2 normalize q and k per (t, k-head) on fp16 buffers; fold 128^-0.5 into q.
// ---------------------------------------------------------------------------
__global__ __launch_bounds__(64) void l2norm_qk(_Float16* __restrict__ qc,
                                                _Float16* __restrict__ kc) {
    const int b = blockIdx.x;
    const int t = b >> 4;
    const int hh = b & 15;
    _Float16* p;
    float extra;
    if (hh < 8) { p = qc + t * 1024 + hh * 128; extra = 0.08838834764831845f; }
    else        { p = kc + t * 1024 + (hh - 8) * 128; extra = 1.f; }
    const int j = threadIdx.x * 2;
    half2t x = *(const half2t*)(p + j);
    const float x0 = (float)x[0], x1 = (float)x[1];
    float ss = x0 * x0 + x1 * x1;
#pragma unroll
    for (int m = 1; m < 64; m <<= 1) ss += __shfl_xor(ss, m, 64);
    const float r = rsqrtf(ss + 1e-6f) * extra;
    half2t y; y[0] = (_Float16)(x0 * r); y[1] = (_Float16)(x1 * r);
    *(half2t*)(p + j) = y;
}

// ---------------------------------------------------------------------------
// Gates: beta = sigmoid(b); lgd = log-decay = -exp(A_log)*softplus(a+dt_bias)
// ---------------------------------------------------------------------------
__global__ __launch_bounds__(256) void gates(const float* __restrict__ ba,
                                             const float* __restrict__ dt_bias,
                                             const float* __restrict__ A_log,
                                             float* __restrict__ lgd,
                                             float* __restrict__ bet) {
    const int i = blockIdx.x * 256 + threadIdx.x;
    const int t = i >> 4;
    const int vh = i & 15;
    const int kh = vh >> 1;
    const int r = vh & 1;
    const float b = ba[t * 32 + kh * 4 + r];
    const float a = ba[t * 32 + kh * 4 + 2 + r];
    bet[i] = 1.f / (1.f + expf(-b));
    const float x = a + dt_bias[vh];
    const float sp = (x > 0.f) ? (x + log1pf(expf(-x))) : log1pf(expf(x));
    lgd[i] = -expf(A_log[vh]) * sp;
}

// ---------------------------------------------------------------------------
// chunk_prep: per (chunk c, v-head h), fully parallel (256 blocks).
// Outputs fp16 blob per chunk-head: U[64x128] Wt[128x64] Kh[128x64]
//   Qg[64x128] L[64x64]  (36864 halves)
// ---------------------------------------------------------------------------
__global__ __launch_bounds__(256) void chunk_prep(
    const _Float16* __restrict__ qch, const _Float16* __restrict__ kch,
    const _Float16* __restrict__ vch, const float* __restrict__ lgd,
    const float* __restrict__ bet, _Float16* __restrict__ CH,
    float* __restrict__ gamC) {
    const int blk = blockIdx.x;
    const int c = blk >> 4, h = blk & 15, kh = h >> 1;
    const int c0 = c * 64;
    const int tid = threadIdx.x, lane = tid & 63, wave = tid >> 6;
    const int l15 = lane & 15, quad = lane >> 4;

    __shared__ __align__(16) _Float16 Ksh[8192];  // [t][kc sw][8]
    __shared__ __align__(16) _Float16 Qsh[8192];
    __shared__ float Amat[64 * 65];
    __shared__ float Gs[64], Bets[64], Gam[64];

    {
        const int t = tid >> 2, kc0 = (tid & 3) * 4;
        const size_t gb = (size_t)(c0 + t) * 1024 + kh * 128;
#pragma unroll
        for (int i = 0; i < 4; ++i) {
            const int kc = kc0 + i;
            half8 kv = *(const half8*)(kch + gb + kc * 8);
            half8 qv = *(const half8*)(qch + gb + kc * 8);
            const int chl = t * 16 + (kc ^ (t & 15));
            *(half8*)&Ksh[chl * 8] = kv;
            *(half8*)&Qsh[chl * 8] = qv;
        }
    }
    if (tid < 64) {
        float g = lgd[(size_t)(c0 + tid) * 16 + h];
#pragma unroll
        for (int off = 1; off < 64; off <<= 1) {
            float y = __shfl_up(g, off, 64);
            if (tid >= off) g += y;
        }
        Gs[tid] = g;
        Gam[tid] = expf(g);
        Bets[tid] = bet[(size_t)(c0 + tid) * 16 + h];
    }
    __syncthreads();

    _Float16* CHb = CH + (size_t)(c * 16 + h) * 36864;
    _Float16* Ug = CHb;
    _Float16* Wtg = CHb + 8192;
    _Float16* Khg = CHb + 16384;
    _Float16* Qgg = CHb + 24576;
    _Float16* Lg = CHb + 32768;

    {
        floatx4 accKK[4], accQK[4];
#pragma unroll
        for (int tt = 0; tt < 4; ++tt) { accKK[tt] = 0; accQK[tt] = 0; }
        half8 bfK[4];
#pragma unroll
        for (int ks = 0; ks < 4; ++ks) {
            const int i = wave * 16 + l15;
            const int kc = ks * 4 + quad;
            bfK[ks] = *(const half8*)&Ksh[(i * 16 + (kc ^ (i & 15))) * 8];
        }
#pragma unroll
        for (int tt = 0; tt < 4; ++tt) {
            const int t = tt * 16 + l15;
#pragma unroll
            for (int ks = 0; ks < 4; ++ks) {
                const int kc = ks * 4 + quad;
                const int chl = (t * 16 + (kc ^ (t & 15))) * 8;
                half8 afK = *(const half8*)&Ksh[chl];
                half8 afQ = *(const half8*)&Qsh[chl];
                accKK[tt] = __builtin_amdgcn_mfma_f32_16x16x32_f16(afK, bfK[ks], accKK[tt], 0, 0, 0);
                accQK[tt] = __builtin_amdgcn_mfma_f32_16x16x32_f16(afQ, bfK[ks], accQK[tt], 0, 0, 0);
            }
        }
        const int ii = wave * 16 + l15;
        const float Gi = Gs[ii];
#pragma unroll
        for (int tt = 0; tt < 4; ++tt)
#pragma unroll
            for (int r = 0; r < 4; ++r) {
                const int t = tt * 16 + quad * 4 + r;
                const float Gt = Gs[t];
                const float ratio = (ii <= t) ? expf(Gt - Gi) : 0.f;
                if (ii < t) Amat[t * 65 + ii] = Bets[t] * ratio * accKK[tt][r];
                Lg[t * 64 + ii] = (_Float16)((ii <= t) ? ratio * accQK[tt][r] : 0.f);
            }
    }
    __syncthreads();

    {
        const int j = tid;
        float x[64];
        if (j < 128) {
#pragma unroll
            for (int t = 0; t < 64; ++t)
                x[t] = Bets[t] * (float)vch[(size_t)(c0 + t) * 2048 + h * 128 + j];
        } else {
            const int k = j - 128;
#pragma unroll
            for (int t = 0; t < 64; ++t) {
                const int chl = t * 16 + ((k >> 3) ^ (t & 15));
                x[t] = Bets[t] * Gam[t] * (float)Ksh[chl * 8 + (k & 7)];
            }
        }
#pragma unroll
        for (int t = 1; t < 64; ++t) {
            float acc = 0.f;
#pragma unroll
            for (int i = 0; i < t; ++i) acc = fmaf(Amat[t * 65 + i], x[i], acc);
            x[t] -= acc;
        }
        if (j < 128) {
#pragma unroll
            for (int t = 0; t < 64; t += 4) {
                half4 w4;
                w4[0] = (_Float16)x[t]; w4[1] = (_Float16)x[t + 1];
                w4[2] = (_Float16)x[t + 2]; w4[3] = (_Float16)x[t + 3];
                *(half4*)&Wtg[j * 64 + t] = w4;
            }
        } else {
            const int k = j - 128;
#pragma unroll
            for (int t = 0; t < 64; ++t) Ug[t * 128 + k] = (_Float16)x[t];
        }
    }

    {
        const float g63 = Gs[63];
        const int k = tid >> 1, cb = (tid & 1) * 32;
#pragma unroll
        for (int cc = 0; cc < 32; cc += 4) {
            half4 o4;
#pragma unroll
            for (int u = 0; u < 4; ++u) {
                const int ci = cb + cc + u;
                const int chl = ci * 16 + ((k >> 3) ^ (ci & 15));
                o4[u] = (_Float16)(expf(g63 - Gs[ci]) * (float)Ksh[chl * 8 + (k & 7)]);
            }
            *(half4*)&Khg[k * 64 + cb + cc] = o4;
        }
        const int cq = tid >> 2, kb = (tid & 3) * 4;
        const float gam = Gam[cq];
#pragma unroll
        for (int kc = 0; kc < 4; ++kc) {
            const int kcc = kb + kc;
            half8 q8 = *(const half8*)&Qsh[(cq * 16 + (kcc ^ (cq & 15))) * 8];
            half8 s8;
#pragma unroll
            for (int u = 0; u < 8; ++u) s8[u] = (_Float16)(gam * (float)q8[u]);
            *(half8*)&Qgg[cq * 128 + kcc * 8] = s8;
        }
        if (tid == 0) gamC[c * 16 + h] = Gam[63];
    }
}

// ---------------------------------------------------------------------------
// chunk_scan v2 (unchanged from R7): 32 blocks, LDS-staged operands.
// ---------------------------------------------------------------------------
__global__ __launch_bounds__(256) void chunk_scan(const _Float16* __restrict__ CH,
                                                  const float* __restrict__ gamC,
                                                  float* __restrict__ o) {
    const int h = blockIdx.x >> 1, vs = blockIdx.x & 1;
    const int tid = threadIdx.x, lane = tid & 63, wave = tid >> 6;
    const int l15 = lane & 15, quad = lane >> 4;
    const int vrow = wave * 16 + l15;

    __shared__ __align__(16) _Float16 Sh[8192];
    __shared__ __align__(16) _Float16 Dt[4096];
    __shared__ __align__(16) _Float16 LUg[8704];
    __shared__ __align__(16) _Float16 LWt[4608];
    __shared__ __align__(16) _Float16 LKh[9216];
    __shared__ __align__(16) _Float16 LQg[8704];
    __shared__ __align__(16) _Float16 LLg[4608];

    floatx4 Sacc[8];
#pragma unroll
    for (int kt = 0; kt < 8; ++kt) Sacc[kt] = 0;
    for (int i = tid; i < 1024; i += 256) *(int4*)&Sh[i * 8] = make_int4(0, 0, 0, 0);
    __syncthreads();

    for (int c = 0; c < 16; ++c) {
        const _Float16* CHb = CH + (size_t)(c * 16 + h) * 36864;
        {
            const int4* src = (const int4*)CHb;
#pragma unroll
            for (int i = 0; i < 4; ++i) {
                const int idx = tid + i * 256;
                *(int4*)&LUg[((idx >> 4) * 17 + (idx & 15)) * 8] = src[idx];
            }
        }
        {
            const int4* src = (const int4*)(CHb + 8192 + vs * 4096);
#pragma unroll
            for (int i = 0; i < 2; ++i) {
                const int idx = tid + i * 256;
                *(int4*)&LWt[((idx >> 3) * 9 + (idx & 7)) * 8] = src[idx];
            }
        }
        {
            const int4* src = (const int4*)(CHb + 16384);
#pragma unroll
            for (int i = 0; i < 4; ++i) {
                const int idx = tid + i * 256;
                *(int4*)&LKh[((idx >> 3) * 9 + (idx & 7)) * 8] = src[idx];
            }
        }
        {
            const int4* src = (const int4*)(CHb + 24576);
#pragma unroll
            for (int i = 0; i < 4; ++i) {
                const int idx = tid + i * 256;
                *(int4*)&LQg[((idx >> 4) * 17 + (idx & 15)) * 8] = src[idx];
            }
        }
        {
            const int4* src = (const int4*)(CHb + 32768);
#pragma unroll
            for (int i = 0; i < 2; ++i) {
                const int idx = tid + i * 256;
                *(int4*)&LLg[((idx >> 3) * 9 + (idx & 7)) * 8] = src[idx];
            }
        }
        __syncthreads();

        half8 bs[4];
#pragma unroll
        for (int ks = 0; ks < 4; ++ks) {
            const int kc = ks * 4 + quad;
            bs[ks] = *(const half8*)&Sh[(vrow * 16 + (kc ^ (vrow & 15))) * 8];
        }
#pragma unroll
        for (int ct = 0; ct < 4; ++ct) {
            floatx4 xa = {0.f, 0.f, 0.f, 0.f};
#pragma unroll
            for (int ks = 0; ks < 4; ++ks) {
                half8 af = *(const half8*)&LUg[((ct * 16 + l15) * 17 + ks * 4 + quad) * 8];
                xa = __builtin_amdgcn_mfma_f32_16x16x32_f16(af, bs[ks], xa, 0, 0, 0);
            }
            half4 w4 = *(const half4*)&LWt[(vrow * 9 + ct * 2 + (quad >> 1)) * 8 + (quad & 1) * 4];
            half4 d4;
#pragma unroll
            for (int r = 0; r < 4; ++r) d4[r] = (_Float16)((float)w4[r] - xa[r]);
            const int cc = ct * 2 + (quad >> 1);
            *(half4*)&Dt[(vrow * 8 + (cc ^ (vrow & 7))) * 8 + (quad & 1) * 4] = d4;
        }
        half8 bd[2];
#pragma unroll
        for (int cs = 0; cs < 2; ++cs) {
            const int cc = cs * 4 + quad;
            bd[cs] = *(const half8*)&Dt[(vrow * 8 + (cc ^ (vrow & 7))) * 8];
        }
#pragma unroll
        for (int ct = 0; ct < 4; ++ct) {
            floatx4 oa = {0.f, 0.f, 0.f, 0.f};
#pragma unroll
            for (int ks = 0; ks < 4; ++ks) {
                half8 af = *(const half8*)&LQg[((ct * 16 + l15) * 17 + ks * 4 + quad) * 8];
                oa = __builtin_amdgcn_mfma_f32_16x16x32_f16(af, bs[ks], oa, 0, 0, 0);
            }
#pragma unroll
            for (int cs = 0; cs < 2; ++cs) {
                half8 af = *(const half8*)&LLg[((ct * 16 + l15) * 9 + cs * 4 + quad) * 8];
                oa = __builtin_amdgcn_mfma_f32_16x16x32_f16(af, bd[cs], oa, 0, 0, 0);
            }
            const int tg = c * 64 + ct * 16 + quad * 4;
            const int col = h * 128 + vs * 64 + vrow;
#pragma unroll
            for (int r = 0; r < 4; ++r) o[(size_t)(tg + r) * 2048 + col] = oa[r];
        }
        const float gC = gamC[c * 16 + h];
#pragma unroll
        for (int kt = 0; kt < 8; ++kt) {
#pragma unroll
            for (int r = 0; r < 4; ++r) Sacc[kt][r] *= gC;
#pragma unroll
            for (int cs = 0; cs < 2; ++cs) {
                half8 af = *(const half8*)&LKh[((kt * 16 + l15) * 9 + cs * 4 + quad) * 8];
                Sacc[kt] = __builtin_amdgcn_mfma_f32_16x16x32_f16(af, bd[cs], Sacc[kt], 0, 0, 0);
            }
        }
#pragma unroll
        for (int kt = 0; kt < 8; ++kt) {
            const int kc = kt * 2 + (quad >> 1);
            half4 s4;
#pragma unroll
            for (int r = 0; r < 4; ++r) s4[r] = (_Float16)Sacc[kt][r];
            *(half4*)&Sh[(vrow * 16 + (kc ^ (vrow & 15))) * 8 + (quad & 1) * 4] = s4;
        }
        __syncthreads();
    }
}

// ---------------------------------------------------------------------------
// Gated RMSNorm: xf = o * silu(z); xn = xf * rsqrt(mean(xf^2)+eps) * w
// ---------------------------------------------------------------------------
__global__ __launch_bounds__(64) void gated_norm(const float* __restrict__ o,
                                                 const float* __restrict__ qkvz,
                                                 const float* __restrict__ nw,
                                                 float* __restrict__ xn) {
    const int b = blockIdx.x;
    const int t = b >> 4;
    const int vh = b & 15;
    const int kh = vh >> 1;
    const int r = vh & 1;
    const float* op = o + (size_t)t * 2048 + vh * 128;
    const float* zp = qkvz + (size_t)t * QKVZ_N + kh * 768 + 512 + r * 128;
    const int j = threadIdx.x * 2;
    const float2 ov = *(const float2*)(op + j);
    const float2 zv = *(const float2*)(zp + j);
    const float f0 = ov.x * zv.x / (1.f + expf(-zv.x));
    const float f1 = ov.y * zv.y / (1.f + expf(-zv.y));
    float ss = f0 * f0 + f1 * f1;
#pragma unroll
    for (int m = 1; m < 64; m <<= 1) ss += __shfl_xor(ss, m, 64);
    const float rs = rsqrtf(ss * (1.f / 128.f) + 1e-6f);
    float* xp = xn + (size_t)t * 2048 + vh * 128;
    *(float2*)(xp + j) = make_float2(f0 * rs * nw[j], f1 * rs * nw[j + 1]);
}

// ---------------------------------------------------------------------------
extern "C" void kernel_launch(void* const* d_in, const int* in_sizes, int n_in,
                              void* d_out, int out_size, void* d_ws, size_t ws_size,
                              hipStream_t stream) {
    const float* hidden  = (const float*)d_in[0];
    const float* w_qkvz  = (const float*)d_in[1];
    const float* w_ba    = (const float*)d_in[2];
    const float* conv_w  = (const float*)d_in[3];
    const float* dt_bias = (const float*)d_in[4];
    const float* A_log   = (const float*)d_in[5];
    const float* norm_w  = (const float*)d_in[6];
    const float* w_out   = (const float*)d_in[7];
    float* out = (float*)d_out;

    char* w = (char*)d_ws;
    float*     qkvz = (float*)(w);                      // 25,165,824 B
    float*     ba   = (float*)(w + 25165824);           //    131,072 B
    _Float16*  qch  = (_Float16*)(w + 25296896);        //  2,097,152 B
    _Float16*  kch  = (_Float16*)(w + 27394048);        //  2,097,152 B
    _Float16*  vch  = (_Float16*)(w + 29491200);        //  4,194,304 B
    float*     lgd  = (float*)(w + 33685504);           //     65,536 B
    float*     bet  = (float*)(w + 33751040);           //     65,536 B
    float*     gamC = (float*)(w + 33816576);           //      4,096 B (pad)
    float*     o    = (float*)(w + 33820672);           //  8,388,608 B
    _Float16*  CH   = (_Float16*)(w + 42209280);        // 18,874,368 B
    float*     xn   = (float*)(w + 42209280);           // overlaps CH (CH dead
                                                        // before xn write)

    gemm_f16<<<dim3(T_LEN / 128, QKVZ_N / 128), 256, 0, stream>>>(hidden, w_qkvz, qkvz,
                                                                  T_LEN, QKVZ_N, HIDDEN);
    gemm_ba<<<T_LEN, 256, 0, stream>>>(hidden, w_ba, ba);
    conv_silu<<<(T_LEN * 4096) / 256, 256, 0, stream>>>(qkvz, conv_w, qch, kch, vch);
    l2norm_qk<<<T_LEN * 16, 64, 0, stream>>>(qch, kch);
    gates<<<(T_LEN * 16) / 256, 256, 0, stream>>>(ba, dt_bias, A_log, lgd, bet);
    chunk_prep<<<256, 256, 0, stream>>>(qch, kch, vch, lgd, bet, CH, gamC);
    chunk_scan<<<32, 256, 0, stream>>>(CH, gamC, o);
    gated_norm<<<T_LEN * 16, 64, 0, stream>>>(o, qkvz, norm_w, xn);
    gemm_f16<<<dim3(T_LEN / 128, VAL_DIM / 128), 256, 0, stream>>>(xn, w_out, out,
                                                                   T_LEN, VAL_DIM, HIDDEN);
}

// Round 9
// 333.879 us; speedup vs baseline: 4.6754x; 1.1551x over previous
//
#include <hip/hip_runtime.h>
#include <math.h>

// ---------------- problem constants ----------------
#define T_LEN   1024
#define HIDDEN  2048
#define QKVZ_N  6144   // 2*KEY_DIM + 2*VALUE_DIM
#define VAL_DIM 2048

typedef _Float16 half8 __attribute__((ext_vector_type(8)));
typedef _Float16 half4 __attribute__((ext_vector_type(4)));
typedef _Float16 half2t __attribute__((ext_vector_type(2)));
typedef float floatx4 __attribute__((ext_vector_type(4)));

__device__ __forceinline__ float sigmoidf_(float x) { return 1.f / (1.f + expf(-x)); }

// ---------------------------------------------------------------------------
// fp32 -> fp16 bulk convert (vectorized, HBM-bound)
// ---------------------------------------------------------------------------
__global__ __launch_bounds__(256) void cvt_h(const float* __restrict__ src,
                                             _Float16* __restrict__ dst, int n4) {
    const int i = blockIdx.x * 256 + threadIdx.x;
    if (i < n4) {
        const float4 v = ((const float4*)src)[i];
        half4 h;
        h[0] = (_Float16)v.x; h[1] = (_Float16)v.y;
        h[2] = (_Float16)v.z; h[3] = (_Float16)v.w;
        *(half4*)&dst[i * 4] = h;
    }
}

// ---------------------------------------------------------------------------
// Pure-fp16 MFMA GEMM: C[M,N] = A[M,K] * W[N,K]^T, fp16 in, OutT out.
// 128x128 tile, BK=32, 4 waves 2x2, 4x4 frags of v_mfma_f32_16x16x32_f16.
// No in-loop cvt (inputs pre-converted).  XCD-aware block swizzle: all 8
// m-blocks of one n-block share ell%8 -> same XCD under round-robin -> each
// W-tile fetched into exactly one L2 (R8: m-fastest put them on 8 XCDs ->
// FETCH 200 MB vs 58 MB unique).
// ---------------------------------------------------------------------------
template <typename OutT>
__global__ __launch_bounds__(256) void gemm_h16(const _Float16* __restrict__ A,
                                                const _Float16* __restrict__ W,
                                                OutT* __restrict__ C,
                                                int MB, int NB, int K) {
    const int N = NB * 128;
    const int l = blockIdx.x;
    const int x = l & 7;
    const int tt = l >> 3;
    const int mb = tt % MB;
    const int nb = x + 8 * (tt / MB);
    const int m0 = mb * 128, n0 = nb * 128;

    const int t = threadIdx.x;
    const int kq = t & 3;
    const int r0 = t >> 2;
    const int wave = t >> 6;
    const int lane = t & 63;
    const int wr = (wave >> 1) * 64;
    const int wc = (wave & 1) * 64;
    const int l15 = lane & 15;
    const int quad = lane >> 4;

    __shared__ __align__(16) _Float16 Ah[4096];  // 128 rows x 32 k, swizzled
    __shared__ __align__(16) _Float16 Bh[4096];

    floatx4 acc[4][4];
#pragma unroll
    for (int i = 0; i < 4; ++i)
#pragma unroll
        for (int j = 0; j < 4; ++j) acc[i][j] = 0;

    for (int k0 = 0; k0 < K; k0 += 32) {
        half8 ag[2], bg[2];
#pragma unroll
        for (int p = 0; p < 2; ++p) {
            const int r = r0 + p * 64;
            ag[p] = *(const half8*)(A + (size_t)(m0 + r) * K + k0 + kq * 8);
            bg[p] = *(const half8*)(W + (size_t)(n0 + r) * K + k0 + kq * 8);
        }
        __syncthreads();
#pragma unroll
        for (int p = 0; p < 2; ++p) {
            const int r = r0 + p * 64;
            const int chunk = r * 4 + (kq ^ (r & 3));
            *(half8*)&Ah[chunk * 8] = ag[p];
            *(half8*)&Bh[chunk * 8] = bg[p];
        }
        __syncthreads();
        half8 af[4], bf[4];
#pragma unroll
        for (int mt = 0; mt < 4; ++mt) {
            const int m = wr + mt * 16 + l15;
            af[mt] = *(const half8*)&Ah[(m * 4 + (quad ^ (m & 3))) * 8];
        }
#pragma unroll
        for (int nt = 0; nt < 4; ++nt) {
            const int n = wc + nt * 16 + l15;
            bf[nt] = *(const half8*)&Bh[(n * 4 + (quad ^ (n & 3))) * 8];
        }
#pragma unroll
        for (int mt = 0; mt < 4; ++mt)
#pragma unroll
            for (int nt = 0; nt < 4; ++nt)
                acc[mt][nt] = __builtin_amdgcn_mfma_f32_16x16x32_f16(
                    af[mt], bf[nt], acc[mt][nt], 0, 0, 0);
    }
#pragma unroll
    for (int mt = 0; mt < 4; ++mt)
#pragma unroll
        for (int nt = 0; nt < 4; ++nt) {
            const int c = n0 + wc + nt * 16 + l15;
#pragma unroll
            for (int reg = 0; reg < 4; ++reg) {
                const int r = m0 + wr + mt * 16 + quad * 4 + reg;
                C[(size_t)r * N + c] = (OutT)acc[mt][nt][reg];
            }
        }
}

// ---------------------------------------------------------------------------
// ba projection: C[1024,32] = A[1024,2048]*W[32,2048]^T (fp32, latency-opt)
// ---------------------------------------------------------------------------
__global__ __launch_bounds__(256) void gemm_ba(const float* __restrict__ A,
                                               const float* __restrict__ W,
                                               float* __restrict__ C) {
    const int m = blockIdx.x;
    const int tid = threadIdx.x;
    const int kl = tid & 31;
    const int ng = tid >> 5;
    const float* Arow = A + (size_t)m * 2048;

    float4 a4[16];
#pragma unroll
    for (int j = 0; j < 16; ++j)
        a4[j] = *(const float4*)(Arow + j * 128 + kl * 4);

#pragma unroll
    for (int nn = 0; nn < 4; ++nn) {
        const int n = nn * 8 + ng;
        const float* Wrow = W + (size_t)n * 2048;
        float acc = 0.f;
#pragma unroll
        for (int j = 0; j < 16; ++j) {
            const float4 w4 = *(const float4*)(Wrow + j * 128 + kl * 4);
            acc = fmaf(a4[j].x, w4.x, acc);
            acc = fmaf(a4[j].y, w4.y, acc);
            acc = fmaf(a4[j].z, w4.z, acc);
            acc = fmaf(a4[j].w, w4.w, acc);
        }
        acc += __shfl_xor(acc, 1, 64);
        acc += __shfl_xor(acc, 2, 64);
        acc += __shfl_xor(acc, 4, 64);
        acc += __shfl_xor(acc, 8, 64);
        acc += __shfl_xor(acc, 16, 64);
        if (kl == 0) C[m * 32 + n] = acc;
    }
}

// ---------------------------------------------------------------------------
// Depthwise causal conv1d (K=4) + SiLU; fp16 in (qkvz), fp16 out q/k/v.
// qkvz row layout per k-head block of 768: [q 128 | k 128 | v 256 | z 256]
// ---------------------------------------------------------------------------
__global__ __launch_bounds__(256) void conv_silu(const _Float16* __restrict__ qkvz,
                                                 const float* __restrict__ conv_w,
                                                 _Float16* __restrict__ qc,
                                                 _Float16* __restrict__ kc,
                                                 _Float16* __restrict__ vc) {
    const int idx = blockIdx.x * 256 + threadIdx.x;
    const int t = idx >> 12;
    const int c = idx & 4095;
    int col;
    _Float16* dst;
    if (c < 1024) {
        col = ((c >> 7) * 768) + (c & 127);
        dst = qc + t * 1024 + c;
    } else if (c < 2048) {
        const int cc = c - 1024;
        col = ((cc >> 7) * 768) + 128 + (cc & 127);
        dst = kc + t * 1024 + cc;
    } else {
        const int cc = c - 2048;
        col = ((cc >> 8) * 768) + 256 + (cc & 255);
        dst = vc + t * 2048 + cc;
    }
    const float w0 = conv_w[c * 4 + 0];
    const float w1 = conv_w[c * 4 + 1];
    const float w2 = conv_w[c * 4 + 2];
    const float w3 = conv_w[c * 4 + 3];
    float acc = (float)qkvz[(size_t)t * QKVZ_N + col] * w3;
    if (t >= 1) acc = fmaf((float)qkvz[(size_t)(t - 1) * QKVZ_N + col], w2, acc);
    if (t >= 2) acc = fmaf((float)qkvz[(size_t)(t - 2) * QKVZ_N + col], w1, acc);
    if (t >= 3) acc = fmaf((float)qkvz[(size_t)(t - 3) * QKVZ_N + col], w0, acc);
    *dst = (_Float16)(acc * sigmoidf_(acc));
}

// ---------------------------------------------------------------------------
// L2 normalize q and k per (t, k-head) on fp16 buffers; fold 128^-0.5 into q.
// ---------------------------------------------------------------------------
__global__ __launch_bounds__(64) void l2norm_qk(_Float16* __restrict__ qc,
                                                _Float16* __restrict__ kc) {
    const int b = blockIdx.x;
    const int t = b >> 4;
    const int hh = b & 15;
    _Float16* p;
    float extra;
    if (hh < 8) { p = qc + t * 1024 + hh * 128; extra = 0.08838834764831845f; }
    else        { p = kc + t * 1024 + (hh - 8) * 128; extra = 1.f; }
    const int j = threadIdx.x * 2;
    half2t x = *(const half2t*)(p + j);
    const float x0 = (float)x[0], x1 = (float)x[1];
    float ss = x0 * x0 + x1 * x1;
#pragma unroll
    for (int m = 1; m < 64; m <<= 1) ss += __shfl_xor(ss, m, 64);
    const float r = rsqrtf(ss + 1e-6f) * extra;
    half2t y; y[0] = (_Float16)(x0 * r); y[1] = (_Float16)(x1 * r);
    *(half2t*)(p + j) = y;
}

// ---------------------------------------------------------------------------
// Gates: beta = sigmoid(b); lgd = log-decay = -exp(A_log)*softplus(a+dt_bias)
// ---------------------------------------------------------------------------
__global__ __launch_bounds__(256) void gates(const float* __restrict__ ba,
                                             const float* __restrict__ dt_bias,
                                             const float* __restrict__ A_log,
                                             float* __restrict__ lgd,
                                             float* __restrict__ bet) {
    const int i = blockIdx.x * 256 + threadIdx.x;
    const int t = i >> 4;
    const int vh = i & 15;
    const int kh = vh >> 1;
    const int r = vh & 1;
    const float b = ba[t * 32 + kh * 4 + r];
    const float a = ba[t * 32 + kh * 4 + 2 + r];
    bet[i] = 1.f / (1.f + expf(-b));
    const float x = a + dt_bias[vh];
    const float sp = (x > 0.f) ? (x + log1pf(expf(-x))) : log1pf(expf(x));
    lgd[i] = -expf(A_log[vh]) * sp;
}

// ---------------------------------------------------------------------------
// chunk_prep (unchanged): per (chunk c, v-head h), fully parallel (256 blocks)
// ---------------------------------------------------------------------------
__global__ __launch_bounds__(256) void chunk_prep(
    const _Float16* __restrict__ qch, const _Float16* __restrict__ kch,
    const _Float16* __restrict__ vch, const float* __restrict__ lgd,
    const float* __restrict__ bet, _Float16* __restrict__ CH,
    float* __restrict__ gamC) {
    const int blk = blockIdx.x;
    const int c = blk >> 4, h = blk & 15, kh = h >> 1;
    const int c0 = c * 64;
    const int tid = threadIdx.x, lane = tid & 63, wave = tid >> 6;
    const int l15 = lane & 15, quad = lane >> 4;

    __shared__ __align__(16) _Float16 Ksh[8192];
    __shared__ __align__(16) _Float16 Qsh[8192];
    __shared__ float Amat[64 * 65];
    __shared__ float Gs[64], Bets[64], Gam[64];

    {
        const int t = tid >> 2, kc0 = (tid & 3) * 4;
        const size_t gb = (size_t)(c0 + t) * 1024 + kh * 128;
#pragma unroll
        for (int i = 0; i < 4; ++i) {
            const int kc = kc0 + i;
            half8 kv = *(const half8*)(kch + gb + kc * 8);
            half8 qv = *(const half8*)(qch + gb + kc * 8);
            const int chl = t * 16 + (kc ^ (t & 15));
            *(half8*)&Ksh[chl * 8] = kv;
            *(half8*)&Qsh[chl * 8] = qv;
        }
    }
    if (tid < 64) {
        float g = lgd[(size_t)(c0 + tid) * 16 + h];
#pragma unroll
        for (int off = 1; off < 64; off <<= 1) {
            float y = __shfl_up(g, off, 64);
            if (tid >= off) g += y;
        }
        Gs[tid] = g;
        Gam[tid] = expf(g);
        Bets[tid] = bet[(size_t)(c0 + tid) * 16 + h];
    }
    __syncthreads();

    _Float16* CHb = CH + (size_t)(c * 16 + h) * 36864;
    _Float16* Ug = CHb;
    _Float16* Wtg = CHb + 8192;
    _Float16* Khg = CHb + 16384;
    _Float16* Qgg = CHb + 24576;
    _Float16* Lg = CHb + 32768;

    {
        floatx4 accKK[4], accQK[4];
#pragma unroll
        for (int tt = 0; tt < 4; ++tt) { accKK[tt] = 0; accQK[tt] = 0; }
        half8 bfK[4];
#pragma unroll
        for (int ks = 0; ks < 4; ++ks) {
            const int i = wave * 16 + l15;
            const int kc = ks * 4 + quad;
            bfK[ks] = *(const half8*)&Ksh[(i * 16 + (kc ^ (i & 15))) * 8];
        }
#pragma unroll
        for (int tt = 0; tt < 4; ++tt) {
            const int t = tt * 16 + l15;
#pragma unroll
            for (int ks = 0; ks < 4; ++ks) {
                const int kc = ks * 4 + quad;
                const int chl = (t * 16 + (kc ^ (t & 15))) * 8;
                half8 afK = *(const half8*)&Ksh[chl];
                half8 afQ = *(const half8*)&Qsh[chl];
                accKK[tt] = __builtin_amdgcn_mfma_f32_16x16x32_f16(afK, bfK[ks], accKK[tt], 0, 0, 0);
                accQK[tt] = __builtin_amdgcn_mfma_f32_16x16x32_f16(afQ, bfK[ks], accQK[tt], 0, 0, 0);
            }
        }
        const int ii = wave * 16 + l15;
        const float Gi = Gs[ii];
#pragma unroll
        for (int tt = 0; tt < 4; ++tt)
#pragma unroll
            for (int r = 0; r < 4; ++r) {
                const int t = tt * 16 + quad * 4 + r;
                const float Gt = Gs[t];
                const float ratio = (ii <= t) ? expf(Gt - Gi) : 0.f;
                if (ii < t) Amat[t * 65 + ii] = Bets[t] * ratio * accKK[tt][r];
                Lg[t * 64 + ii] = (_Float16)((ii <= t) ? ratio * accQK[tt][r] : 0.f);
            }
    }
    __syncthreads();

    {
        const int j = tid;
        float x[64];
        if (j < 128) {
#pragma unroll
            for (int t = 0; t < 64; ++t)
                x[t] = Bets[t] * (float)vch[(size_t)(c0 + t) * 2048 + h * 128 + j];
        } else {
            const int k = j - 128;
#pragma unroll
            for (int t = 0; t < 64; ++t) {
                const int chl = t * 16 + ((k >> 3) ^ (t & 15));
                x[t] = Bets[t] * Gam[t] * (float)Ksh[chl * 8 + (k & 7)];
            }
        }
#pragma unroll
        for (int t = 1; t < 64; ++t) {
            float acc = 0.f;
#pragma unroll
            for (int i = 0; i < t; ++i) acc = fmaf(Amat[t * 65 + i], x[i], acc);
            x[t] -= acc;
        }
        if (j < 128) {
#pragma unroll
            for (int t = 0; t < 64; t += 4) {
                half4 w4;
                w4[0] = (_Float16)x[t]; w4[1] = (_Float16)x[t + 1];
                w4[2] = (_Float16)x[t + 2]; w4[3] = (_Float16)x[t + 3];
                *(half4*)&Wtg[j * 64 + t] = w4;
            }
        } else {
            const int k = j - 128;
#pragma unroll
            for (int t = 0; t < 64; ++t) Ug[t * 128 + k] = (_Float16)x[t];
        }
    }

    {
        const float g63 = Gs[63];
        const int k = tid >> 1, cb = (tid & 1) * 32;
#pragma unroll
        for (int cc = 0; cc < 32; cc += 4) {
            half4 o4;
#pragma unroll
            for (int u = 0; u < 4; ++u) {
                const int ci = cb + cc + u;
                const int chl = ci * 16 + ((k >> 3) ^ (ci & 15));
                o4[u] = (_Float16)(expf(g63 - Gs[ci]) * (float)Ksh[chl * 8 + (k & 7)]);
            }
            *(half4*)&Khg[k * 64 + cb + cc] = o4;
        }
        const int cq = tid >> 2, kb = (tid & 3) * 4;
        const float gam = Gam[cq];
#pragma unroll
        for (int kc = 0; kc < 4; ++kc) {
            const int kcc = kb + kc;
            half8 q8 = *(const half8*)&Qsh[(cq * 16 + (kcc ^ (cq & 15))) * 8];
            half8 s8;
#pragma unroll
            for (int u = 0; u < 8; ++u) s8[u] = (_Float16)(gam * (float)q8[u]);
            *(half8*)&Qgg[cq * 128 + kcc * 8] = s8;
        }
        if (tid == 0) gamC[c * 16 + h] = Gam[63];
    }
}

// ---------------------------------------------------------------------------
// chunk_scan (unchanged from R7): 32 blocks, LDS-staged operands.
// ---------------------------------------------------------------------------
__global__ __launch_bounds__(256) void chunk_scan(const _Float16* __restrict__ CH,
                                                  const float* __restrict__ gamC,
                                                  float* __restrict__ o) {
    const int h = blockIdx.x >> 1, vs = blockIdx.x & 1;
    const int tid = threadIdx.x, lane = tid & 63, wave = tid >> 6;
    const int l15 = lane & 15, quad = lane >> 4;
    const int vrow = wave * 16 + l15;

    __shared__ __align__(16) _Float16 Sh[8192];
    __shared__ __align__(16) _Float16 Dt[4096];
    __shared__ __align__(16) _Float16 LUg[8704];
    __shared__ __align__(16) _Float16 LWt[4608];
    __shared__ __align__(16) _Float16 LKh[9216];
    __shared__ __align__(16) _Float16 LQg[8704];
    __shared__ __align__(16) _Float16 LLg[4608];

    floatx4 Sacc[8];
#pragma unroll
    for (int kt = 0; kt < 8; ++kt) Sacc[kt] = 0;
    for (int i = tid; i < 1024; i += 256) *(int4*)&Sh[i * 8] = make_int4(0, 0, 0, 0);
    __syncthreads();

    for (int c = 0; c < 16; ++c) {
        const _Float16* CHb = CH + (size_t)(c * 16 + h) * 36864;
        {
            const int4* src = (const int4*)CHb;
#pragma unroll
            for (int i = 0; i < 4; ++i) {
                const int idx = tid + i * 256;
                *(int4*)&LUg[((idx >> 4) * 17 + (idx & 15)) * 8] = src[idx];
            }
        }
        {
            const int4* src = (const int4*)(CHb + 8192 + vs * 4096);
#pragma unroll
            for (int i = 0; i < 2; ++i) {
                const int idx = tid + i * 256;
                *(int4*)&LWt[((idx >> 3) * 9 + (idx & 7)) * 8] = src[idx];
            }
        }
        {
            const int4* src = (const int4*)(CHb + 16384);
#pragma unroll
            for (int i = 0; i < 4; ++i) {
                const int idx = tid + i * 256;
                *(int4*)&LKh[((idx >> 3) * 9 + (idx & 7)) * 8] = src[idx];
            }
        }
        {
            const int4* src = (const int4*)(CHb + 24576);
#pragma unroll
            for (int i = 0; i < 4; ++i) {
                const int idx = tid + i * 256;
                *(int4*)&LQg[((idx >> 4) * 17 + (idx & 15)) * 8] = src[idx];
            }
        }
        {
            const int4* src = (const int4*)(CHb + 32768);
#pragma unroll
            for (int i = 0; i < 2; ++i) {
                const int idx = tid + i * 256;
                *(int4*)&LLg[((idx >> 3) * 9 + (idx & 7)) * 8] = src[idx];
            }
        }
        __syncthreads();

        half8 bs[4];
#pragma unroll
        for (int ks = 0; ks < 4; ++ks) {
            const int kc = ks * 4 + quad;
            bs[ks] = *(const half8*)&Sh[(vrow * 16 + (kc ^ (vrow & 15))) * 8];
        }
#pragma unroll
        for (int ct = 0; ct < 4; ++ct) {
            floatx4 xa = {0.f, 0.f, 0.f, 0.f};
#pragma unroll
            for (int ks = 0; ks < 4; ++ks) {
                half8 af = *(const half8*)&LUg[((ct * 16 + l15) * 17 + ks * 4 + quad) * 8];
                xa = __builtin_amdgcn_mfma_f32_16x16x32_f16(af, bs[ks], xa, 0, 0, 0);
            }
            half4 w4 = *(const half4*)&LWt[(vrow * 9 + ct * 2 + (quad >> 1)) * 8 + (quad & 1) * 4];
            half4 d4;
#pragma unroll
            for (int r = 0; r < 4; ++r) d4[r] = (_Float16)((float)w4[r] - xa[r]);
            const int cc = ct * 2 + (quad >> 1);
            *(half4*)&Dt[(vrow * 8 + (cc ^ (vrow & 7))) * 8 + (quad & 1) * 4] = d4;
        }
        half8 bd[2];
#pragma unroll
        for (int cs = 0; cs < 2; ++cs) {
            const int cc = cs * 4 + quad;
            bd[cs] = *(const half8*)&Dt[(vrow * 8 + (cc ^ (vrow & 7))) * 8];
        }
#pragma unroll
        for (int ct = 0; ct < 4; ++ct) {
            floatx4 oa = {0.f, 0.f, 0.f, 0.f};
#pragma unroll
            for (int ks = 0; ks < 4; ++ks) {
                half8 af = *(const half8*)&LQg[((ct * 16 + l15) * 17 + ks * 4 + quad) * 8];
                oa = __builtin_amdgcn_mfma_f32_16x16x32_f16(af, bs[ks], oa, 0, 0, 0);
            }
#pragma unroll
            for (int cs = 0; cs < 2; ++cs) {
                half8 af = *(const half8*)&LLg[((ct * 16 + l15) * 9 + cs * 4 + quad) * 8];
                oa = __builtin_amdgcn_mfma_f32_16x16x32_f16(af, bd[cs], oa, 0, 0, 0);
            }
            const int tg = c * 64 + ct * 16 + quad * 4;
            const int col = h * 128 + vs * 64 + vrow;
#pragma unroll
            for (int r = 0; r < 4; ++r) o[(size_t)(tg + r) * 2048 + col] = oa[r];
        }
        const float gC = gamC[c * 16 + h];
#pragma unroll
        for (int kt = 0; kt < 8; ++kt) {
#pragma unroll
            for (int r = 0; r < 4; ++r) Sacc[kt][r] *= gC;
#pragma unroll
            for (int cs = 0; cs < 2; ++cs) {
                half8 af = *(const half8*)&LKh[((kt * 16 + l15) * 9 + cs * 4 + quad) * 8];
                Sacc[kt] = __builtin_amdgcn_mfma_f32_16x16x32_f16(af, bd[cs], Sacc[kt], 0, 0, 0);
            }
        }
#pragma unroll
        for (int kt = 0; kt < 8; ++kt) {
            const int kc = kt * 2 + (quad >> 1);
            half4 s4;
#pragma unroll
            for (int r = 0; r < 4; ++r) s4[r] = (_Float16)Sacc[kt][r];
            *(half4*)&Sh[(vrow * 16 + (kc ^ (vrow & 15))) * 8 + (quad & 1) * 4] = s4;
        }
        __syncthreads();
    }
}

// ---------------------------------------------------------------------------
// Gated RMSNorm: xf = o * silu(z); xn = xf * rsqrt(mean(xf^2)+eps) * w
// z read from fp16 qkvz; xn written fp16 (feeds fp16 out-GEMM directly).
// ---------------------------------------------------------------------------
__global__ __launch_bounds__(64) void gated_norm(const float* __restrict__ o,
                                                 const _Float16* __restrict__ qkvz,
                                                 const float* __restrict__ nw,
                                                 _Float16* __restrict__ xn) {
    const int b = blockIdx.x;
    const int t = b >> 4;
    const int vh = b & 15;
    const int kh = vh >> 1;
    const int r = vh & 1;
    const float* op = o + (size_t)t * 2048 + vh * 128;
    const _Float16* zp = qkvz + (size_t)t * QKVZ_N + kh * 768 + 512 + r * 128;
    const int j = threadIdx.x * 2;
    const float2 ov = *(const float2*)(op + j);
    const half2t zv = *(const half2t*)(zp + j);
    const float z0 = (float)zv[0], z1 = (float)zv[1];
    const float f0 = ov.x * z0 / (1.f + expf(-z0));
    const float f1 = ov.y * z1 / (1.f + expf(-z1));
    float ss = f0 * f0 + f1 * f1;
#pragma unroll
    for (int m = 1; m < 64; m <<= 1) ss += __shfl_xor(ss, m, 64);
    const float rs = rsqrtf(ss * (1.f / 128.f) + 1e-6f);
    _Float16* xp = xn + (size_t)t * 2048 + vh * 128;
    half2t y;
    y[0] = (_Float16)(f0 * rs * nw[j]);
    y[1] = (_Float16)(f1 * rs * nw[j + 1]);
    *(half2t*)(xp + j) = y;
}

// ---------------------------------------------------------------------------
extern "C" void kernel_launch(void* const* d_in, const int* in_sizes, int n_in,
                              void* d_out, int out_size, void* d_ws, size_t ws_size,
                              hipStream_t stream) {
    const float* hidden  = (const float*)d_in[0];
    const float* w_qkvz  = (const float*)d_in[1];
    const float* w_ba    = (const float*)d_in[2];
    const float* conv_w  = (const float*)d_in[3];
    const float* dt_bias = (const float*)d_in[4];
    const float* A_log   = (const float*)d_in[5];
    const float* norm_w  = (const float*)d_in[6];
    const float* w_out   = (const float*)d_in[7];
    float* out = (float*)d_out;

    // workspace layout (~63.2 MB), with lifetime-based overlaps:
    //   hidden_h overlaps o        (hidden_h dead after qkvz GEMM)
    //   CH + xn_h overlap wqkvz_h  (wqkvz_h dead after qkvz GEMM)
    char* w = (char*)d_ws;
    _Float16*  qkvz_h = (_Float16*)(w);                 // 12,582,912 B (fp16)
    float*     ba     = (float*)(w + 12582912);         //    131,072 B
    _Float16*  qch    = (_Float16*)(w + 12713984);      //  2,097,152 B
    _Float16*  kch    = (_Float16*)(w + 14811136);      //  2,097,152 B
    _Float16*  vch    = (_Float16*)(w + 16908288);      //  4,194,304 B
    float*     lgd    = (float*)(w + 21102592);         //     65,536 B
    float*     bet    = (float*)(w + 21168128);         //     65,536 B
    float*     gamC   = (float*)(w + 21233664);         //      4,096 B
    float*     o      = (float*)(w + 21237760);         //  8,388,608 B
    _Float16*  hid_h  = (_Float16*)(w + 21237760);      //  overlaps o
    _Float16*  wqk_h  = (_Float16*)(w + 29626368);      // 25,165,824 B
    _Float16*  CH     = (_Float16*)(w + 29626368);      //  overlaps wqk_h
    _Float16*  xn_h   = (_Float16*)(w + 29626368 + 18874368);  // after CH
    _Float16*  wout_h = (_Float16*)(w + 54792192);      //  8,388,608 B
    // total: 63,180,800 B

    // fp32 -> fp16 pre-conversions (one-shot, HBM-bound)
    cvt_h<<<(HIDDEN * T_LEN / 4 + 255) / 256, 256, 0, stream>>>(hidden, hid_h,
                                                                HIDDEN * T_LEN / 4);
    cvt_h<<<(QKVZ_N * HIDDEN / 4 + 255) / 256, 256, 0, stream>>>(w_qkvz, wqk_h,
                                                                 QKVZ_N * HIDDEN / 4);
    cvt_h<<<(VAL_DIM * HIDDEN / 4 + 255) / 256, 256, 0, stream>>>(w_out, wout_h,
                                                                  VAL_DIM * HIDDEN / 4);

    gemm_h16<_Float16><<<8 * 48, 256, 0, stream>>>(hid_h, wqk_h, qkvz_h, 8, 48, HIDDEN);
    gemm_ba<<<T_LEN, 256, 0, stream>>>(hidden, w_ba, ba);
    conv_silu<<<(T_LEN * 4096) / 256, 256, 0, stream>>>(qkvz_h, conv_w, qch, kch, vch);
    l2norm_qk<<<T_LEN * 16, 64, 0, stream>>>(qch, kch);
    gates<<<(T_LEN * 16) / 256, 256, 0, stream>>>(ba, dt_bias, A_log, lgd, bet);
    chunk_prep<<<256, 256, 0, stream>>>(qch, kch, vch, lgd, bet, CH, gamC);
    chunk_scan<<<32, 256, 0, stream>>>(CH, gamC, o);
    gated_norm<<<T_LEN * 16, 64, 0, stream>>>(o, qkvz_h, norm_w, xn_h);
    gemm_h16<float><<<8 * 16, 256, 0, stream>>>(xn_h, wout_h, out, 8, 16, HIDDEN);
}

// Round 10
// 316.742 us; speedup vs baseline: 4.9284x; 1.0541x over previous
//
#include <hip/hip_runtime.h>
#include <math.h>

// ---------------- problem constants ----------------
#define T_LEN   1024
#define HIDDEN  2048
#define QKVZ_N  6144   // 2*KEY_DIM + 2*VALUE_DIM
#define VAL_DIM 2048

typedef _Float16 half8 __attribute__((ext_vector_type(8)));
typedef _Float16 half4 __attribute__((ext_vector_type(4)));
typedef _Float16 half2t __attribute__((ext_vector_type(2)));
typedef float floatx4 __attribute__((ext_vector_type(4)));

__device__ __forceinline__ float sigmoidf_(float x) { return 1.f / (1.f + expf(-x)); }

// async global->LDS, 16B per lane; LDS dest = wave-uniform base + lane*16
__device__ __forceinline__ void gl_lds16(const _Float16* g, _Float16* l) {
    __builtin_amdgcn_global_load_lds(
        (const __attribute__((address_space(1))) void*)g,
        (__attribute__((address_space(3))) void*)l, 16, 0, 0);
}

// ---------------------------------------------------------------------------
// fused fp32 -> fp16 bulk convert of the three GEMM operands (1 launch)
// ---------------------------------------------------------------------------
__global__ __launch_bounds__(256) void cvt3(const float* __restrict__ s0, _Float16* __restrict__ d0, int n0,
                                            const float* __restrict__ s1, _Float16* __restrict__ d1, int n1,
                                            const float* __restrict__ s2, _Float16* __restrict__ d2, int n2) {
    int i = blockIdx.x * 256 + threadIdx.x;
    const float* s;
    _Float16* d;
    if (i < n0) { s = s0; d = d0; }
    else if (i < n0 + n1) { s = s1; d = d1; i -= n0; }
    else if (i < n0 + n1 + n2) { s = s2; d = d2; i -= n0 + n1; }
    else return;
    const float4 v = ((const float4*)s)[i];
    half4 h;
    h[0] = (_Float16)v.x; h[1] = (_Float16)v.y;
    h[2] = (_Float16)v.z; h[3] = (_Float16)v.w;
    *(half4*)&d[i * 4] = h;
}

// ---------------------------------------------------------------------------
// Pure-fp16 MFMA GEMM, async-staged: C[M,N] = A[M,K]*W[N,K]^T.
// 128x128 tile, BK=32, 4 waves 2x2, 4x4 frags of v_mfma_f32_16x16x32_f16.
// Staging via global_load_lds width=16 (no VGPR round-trip, no ds_write VALU);
// per-lane global k-chunk permuted (kc = kq ^ (r&3)) so the async lane->slot
// mapping reproduces the XOR-swizzled LDS layout the frag reads expect.
// XCD swizzle: all m-blocks of one n-block share blockIdx%8 -> same XCD L2.
// __launch_bounds__(256,2): 2 blocks/CU so the vmcnt-drain barrier of one
// block is hidden by the other's MFMA stream.
// ---------------------------------------------------------------------------
template <typename OutT>
__global__ __launch_bounds__(256, 2) void gemm_h16(const _Float16* __restrict__ A,
                                                   const _Float16* __restrict__ W,
                                                   OutT* __restrict__ C,
                                                   int MB, int NB, int K) {
    const int N = NB * 128;
    const int l = blockIdx.x;
    const int x = l & 7;
    const int tt = l >> 3;
    const int mb = tt % MB;
    const int nb = x + 8 * (tt / MB);
    const int m0 = mb * 128, n0 = nb * 128;

    const int t = threadIdx.x;
    const int wave = t >> 6;
    const int lane = t & 63;
    const int wr = (wave >> 1) * 64;
    const int wc = (wave & 1) * 64;
    const int l15 = lane & 15;
    const int quad = lane >> 4;

    __shared__ __align__(16) _Float16 Ah[4096];  // 128 rows x 32 k, swizzled
    __shared__ __align__(16) _Float16 Bh[4096];

    // staging coords: lane -> (row within wave's 16-row strip, k-chunk)
    const int sr = lane >> 2;        // 0..15
    const int skq = lane & 3;        // slot k index

    floatx4 acc[4][4];
#pragma unroll
    for (int i = 0; i < 4; ++i)
#pragma unroll
        for (int j = 0; j < 4; ++j) acc[i][j] = 0;

    for (int k0 = 0; k0 < K; k0 += 32) {
        __syncthreads();   // previous iteration's frag reads done
#pragma unroll
        for (int p = 0; p < 2; ++p) {
            const int r = p * 64 + wave * 16 + sr;
            const int kc = skq ^ (r & 3);          // permuted global chunk
            const int lbase = (p * 256 + wave * 64) * 8;  // wave-uniform
            gl_lds16(A + (size_t)(m0 + r) * K + k0 + kc * 8, &Ah[lbase]);
            gl_lds16(W + (size_t)(n0 + r) * K + k0 + kc * 8, &Bh[lbase]);
        }
        __syncthreads();   // drains vmcnt (compiler emits s_waitcnt vmcnt(0))
        half8 af[4], bf[4];
#pragma unroll
        for (int mt = 0; mt < 4; ++mt) {
            const int m = wr + mt * 16 + l15;
            af[mt] = *(const half8*)&Ah[(m * 4 + (quad ^ (m & 3))) * 8];
        }
#pragma unroll
        for (int nt = 0; nt < 4; ++nt) {
            const int n = wc + nt * 16 + l15;
            bf[nt] = *(const half8*)&Bh[(n * 4 + (quad ^ (n & 3))) * 8];
        }
#pragma unroll
        for (int mt = 0; mt < 4; ++mt)
#pragma unroll
            for (int nt = 0; nt < 4; ++nt)
                acc[mt][nt] = __builtin_amdgcn_mfma_f32_16x16x32_f16(
                    af[mt], bf[nt], acc[mt][nt], 0, 0, 0);
    }
#pragma unroll
    for (int mt = 0; mt < 4; ++mt)
#pragma unroll
        for (int nt = 0; nt < 4; ++nt) {
            const int c = n0 + wc + nt * 16 + l15;
#pragma unroll
            for (int reg = 0; reg < 4; ++reg) {
                const int r = m0 + wr + mt * 16 + quad * 4 + reg;
                C[(size_t)r * N + c] = (OutT)acc[mt][nt][reg];
            }
        }
}

// ---------------------------------------------------------------------------
// ba projection fused with gates: per row m compute ba[32] in-block, then
// beta = sigmoid(b), lgd = -exp(A_log)*softplus(a+dt_bias).  1024 blocks.
// ---------------------------------------------------------------------------
__global__ __launch_bounds__(256) void gemm_ba_gates(const float* __restrict__ A,
                                                     const float* __restrict__ W,
                                                     const float* __restrict__ dt_bias,
                                                     const float* __restrict__ A_log,
                                                     float* __restrict__ lgd,
                                                     float* __restrict__ bet) {
    const int m = blockIdx.x;
    const int tid = threadIdx.x;
    const int kl = tid & 31;
    const int ng = tid >> 5;
    const float* Arow = A + (size_t)m * 2048;
    __shared__ float sba[32];

    float4 a4[16];
#pragma unroll
    for (int j = 0; j < 16; ++j)
        a4[j] = *(const float4*)(Arow + j * 128 + kl * 4);

#pragma unroll
    for (int nn = 0; nn < 4; ++nn) {
        const int n = nn * 8 + ng;
        const float* Wrow = W + (size_t)n * 2048;
        float acc = 0.f;
#pragma unroll
        for (int j = 0; j < 16; ++j) {
            const float4 w4 = *(const float4*)(Wrow + j * 128 + kl * 4);
            acc = fmaf(a4[j].x, w4.x, acc);
            acc = fmaf(a4[j].y, w4.y, acc);
            acc = fmaf(a4[j].z, w4.z, acc);
            acc = fmaf(a4[j].w, w4.w, acc);
        }
        acc += __shfl_xor(acc, 1, 64);
        acc += __shfl_xor(acc, 2, 64);
        acc += __shfl_xor(acc, 4, 64);
        acc += __shfl_xor(acc, 8, 64);
        acc += __shfl_xor(acc, 16, 64);
        if (kl == 0) sba[n] = acc;
    }
    __syncthreads();
    if (tid < 16) {
        const int vh = tid, kh = vh >> 1, r = vh & 1;
        const float b = sba[kh * 4 + r];
        const float a = sba[kh * 4 + 2 + r];
        bet[m * 16 + vh] = 1.f / (1.f + expf(-b));
        const float xx = a + dt_bias[vh];
        const float sp = (xx > 0.f) ? (xx + log1pf(expf(-xx))) : log1pf(expf(xx));
        lgd[m * 16 + vh] = -expf(A_log[vh]) * sp;
    }
}

// ---------------------------------------------------------------------------
// Depthwise causal conv1d (K=4) + SiLU; fp16 in (qkvz), fp16 out q/k/v.
// qkvz row layout per k-head block of 768: [q 128 | k 128 | v 256 | z 256]
// ---------------------------------------------------------------------------
__global__ __launch_bounds__(256) void conv_silu(const _Float16* __restrict__ qkvz,
                                                 const float* __restrict__ conv_w,
                                                 _Float16* __restrict__ qc,
                                                 _Float16* __restrict__ kc,
                                                 _Float16* __restrict__ vc) {
    const int idx = blockIdx.x * 256 + threadIdx.x;
    const int t = idx >> 12;
    const int c = idx & 4095;
    int col;
    _Float16* dst;
    if (c < 1024) {
        col = ((c >> 7) * 768) + (c & 127);
        dst = qc + t * 1024 + c;
    } else if (c < 2048) {
        const int cc = c - 1024;
        col = ((cc >> 7) * 768) + 128 + (cc & 127);
        dst = kc + t * 1024 + cc;
    } else {
        const int cc = c - 2048;
        col = ((cc >> 8) * 768) + 256 + (cc & 255);
        dst = vc + t * 2048 + cc;
    }
    const float w0 = conv_w[c * 4 + 0];
    const float w1 = conv_w[c * 4 + 1];
    const float w2 = conv_w[c * 4 + 2];
    const float w3 = conv_w[c * 4 + 3];
    float acc = (float)qkvz[(size_t)t * QKVZ_N + col] * w3;
    if (t >= 1) acc = fmaf((float)qkvz[(size_t)(t - 1) * QKVZ_N + col], w2, acc);
    if (t >= 2) acc = fmaf((float)qkvz[(size_t)(t - 2) * QKVZ_N + col], w1, acc);
    if (t >= 3) acc = fmaf((float)qkvz[(size_t)(t - 3) * QKVZ_N + col], w0, acc);
    *dst = (_Float16)(acc * sigmoidf_(acc));
}

// ---------------------------------------------------------------------------
// L2 normalize q and k per (t, k-head) on fp16 buffers; fold 128^-0.5 into q.
// ---------------------------------------------------------------------------
__global__ __launch_bounds__(64) void l2norm_qk(_Float16* __restrict__ qc,
                                                _Float16* __restrict__ kc) {
    const int b = blockIdx.x;
    const int t = b >> 4;
    const int hh = b & 15;
    _Float16* p;
    float extra;
    if (hh < 8) { p = qc + t * 1024 + hh * 128; extra = 0.08838834764831845f; }
    else        { p = kc + t * 1024 + (hh - 8) * 128; extra = 1.f; }
    const int j = threadIdx.x * 2;
    half2t x = *(const half2t*)(p + j);
    const float x0 = (float)x[0], x1 = (float)x[1];
    float ss = x0 * x0 + x1 * x1;
#pragma unroll
    for (int m = 1; m < 64; m <<= 1) ss += __shfl_xor(ss, m, 64);
    const float r = rsqrtf(ss + 1e-6f) * extra;
    half2t y; y[0] = (_Float16)(x0 * r); y[1] = (_Float16)(x1 * r);
    *(half2t*)(p + j) = y;
}

// ---------------------------------------------------------------------------
// chunk_prep (unchanged): per (chunk c, v-head h), fully parallel (256 blocks)
// ---------------------------------------------------------------------------
__global__ __launch_bounds__(256) void chunk_prep(
    const _Float16* __restrict__ qch, const _Float16* __restrict__ kch,
    const _Float16* __restrict__ vch, const float* __restrict__ lgd,
    const float* __restrict__ bet, _Float16* __restrict__ CH,
    float* __restrict__ gamC) {
    const int blk = blockIdx.x;
    const int c = blk >> 4, h = blk & 15, kh = h >> 1;
    const int c0 = c * 64;
    const int tid = threadIdx.x, lane = tid & 63, wave = tid >> 6;
    const int l15 = lane & 15, quad = lane >> 4;

    __shared__ __align__(16) _Float16 Ksh[8192];
    __shared__ __align__(16) _Float16 Qsh[8192];
    __shared__ float Amat[64 * 65];
    __shared__ float Gs[64], Bets[64], Gam[64];

    {
        const int t = tid >> 2, kc0 = (tid & 3) * 4;
        const size_t gb = (size_t)(c0 + t) * 1024 + kh * 128;
#pragma unroll
        for (int i = 0; i < 4; ++i) {
            const int kc = kc0 + i;
            half8 kv = *(const half8*)(kch + gb + kc * 8);
            half8 qv = *(const half8*)(qch + gb + kc * 8);
            const int chl = t * 16 + (kc ^ (t & 15));
            *(half8*)&Ksh[chl * 8] = kv;
            *(half8*)&Qsh[chl * 8] = qv;
        }
    }
    if (tid < 64) {
        float g = lgd[(size_t)(c0 + tid) * 16 + h];
#pragma unroll
        for (int off = 1; off < 64; off <<= 1) {
            float y = __shfl_up(g, off, 64);
            if (tid >= off) g += y;
        }
        Gs[tid] = g;
        Gam[tid] = expf(g);
        Bets[tid] = bet[(size_t)(c0 + tid) * 16 + h];
    }
    __syncthreads();

    _Float16* CHb = CH + (size_t)(c * 16 + h) * 36864;
    _Float16* Ug = CHb;
    _Float16* Wtg = CHb + 8192;
    _Float16* Khg = CHb + 16384;
    _Float16* Qgg = CHb + 24576;
    _Float16* Lg = CHb + 32768;

    {
        floatx4 accKK[4], accQK[4];
#pragma unroll
        for (int tt = 0; tt < 4; ++tt) { accKK[tt] = 0; accQK[tt] = 0; }
        half8 bfK[4];
#pragma unroll
        for (int ks = 0; ks < 4; ++ks) {
            const int i = wave * 16 + l15;
            const int kc = ks * 4 + quad;
            bfK[ks] = *(const half8*)&Ksh[(i * 16 + (kc ^ (i & 15))) * 8];
        }
#pragma unroll
        for (int tt = 0; tt < 4; ++tt) {
            const int t = tt * 16 + l15;
#pragma unroll
            for (int ks = 0; ks < 4; ++ks) {
                const int kc = ks * 4 + quad;
                const int chl = (t * 16 + (kc ^ (t & 15))) * 8;
                half8 afK = *(const half8*)&Ksh[chl];
                half8 afQ = *(const half8*)&Qsh[chl];
                accKK[tt] = __builtin_amdgcn_mfma_f32_16x16x32_f16(afK, bfK[ks], accKK[tt], 0, 0, 0);
                accQK[tt] = __builtin_amdgcn_mfma_f32_16x16x32_f16(afQ, bfK[ks], accQK[tt], 0, 0, 0);
            }
        }
        const int ii = wave * 16 + l15;
        const float Gi = Gs[ii];
#pragma unroll
        for (int tt = 0; tt < 4; ++tt)
#pragma unroll
            for (int r = 0; r < 4; ++r) {
                const int t = tt * 16 + quad * 4 + r;
                const float Gt = Gs[t];
                const float ratio = (ii <= t) ? expf(Gt - Gi) : 0.f;
                if (ii < t) Amat[t * 65 + ii] = Bets[t] * ratio * accKK[tt][r];
                Lg[t * 64 + ii] = (_Float16)((ii <= t) ? ratio * accQK[tt][r] : 0.f);
            }
    }
    __syncthreads();

    {
        const int j = tid;
        float x[64];
        if (j < 128) {
#pragma unroll
            for (int t = 0; t < 64; ++t)
                x[t] = Bets[t] * (float)vch[(size_t)(c0 + t) * 2048 + h * 128 + j];
        } else {
            const int k = j - 128;
#pragma unroll
            for (int t = 0; t < 64; ++t) {
                const int chl = t * 16 + ((k >> 3) ^ (t & 15));
                x[t] = Bets[t] * Gam[t] * (float)Ksh[chl * 8 + (k & 7)];
            }
        }
#pragma unroll
        for (int t = 1; t < 64; ++t) {
            float acc = 0.f;
#pragma unroll
            for (int i = 0; i < t; ++i) acc = fmaf(Amat[t * 65 + i], x[i], acc);
            x[t] -= acc;
        }
        if (j < 128) {
#pragma unroll
            for (int t = 0; t < 64; t += 4) {
                half4 w4;
                w4[0] = (_Float16)x[t]; w4[1] = (_Float16)x[t + 1];
                w4[2] = (_Float16)x[t + 2]; w4[3] = (_Float16)x[t + 3];
                *(half4*)&Wtg[j * 64 + t] = w4;
            }
        } else {
            const int k = j - 128;
#pragma unroll
            for (int t = 0; t < 64; ++t) Ug[t * 128 + k] = (_Float16)x[t];
        }
    }

    {
        const float g63 = Gs[63];
        const int k = tid >> 1, cb = (tid & 1) * 32;
#pragma unroll
        for (int cc = 0; cc < 32; cc += 4) {
            half4 o4;
#pragma unroll
            for (int u = 0; u < 4; ++u) {
                const int ci = cb + cc + u;
                const int chl = ci * 16 + ((k >> 3) ^ (ci & 15));
                o4[u] = (_Float16)(expf(g63 - Gs[ci]) * (float)Ksh[chl * 8 + (k & 7)]);
            }
            *(half4*)&Khg[k * 64 + cb + cc] = o4;
        }
        const int cq = tid >> 2, kb = (tid & 3) * 4;
        const float gam = Gam[cq];
#pragma unroll
        for (int kc = 0; kc < 4; ++kc) {
            const int kcc = kb + kc;
            half8 q8 = *(const half8*)&Qsh[(cq * 16 + (kcc ^ (cq & 15))) * 8];
            half8 s8;
#pragma unroll
            for (int u = 0; u < 8; ++u) s8[u] = (_Float16)(gam * (float)q8[u]);
            *(half8*)&Qgg[cq * 128 + kcc * 8] = s8;
        }
        if (tid == 0) gamC[c * 16 + h] = Gam[63];
    }
}

// ---------------------------------------------------------------------------
// chunk_scan (unchanged from R7): 32 blocks, LDS-staged operands.
// ---------------------------------------------------------------------------
__global__ __launch_bounds__(256) void chunk_scan(const _Float16* __restrict__ CH,
                                                  const float* __restrict__ gamC,
                                                  float* __restrict__ o) {
    const int h = blockIdx.x >> 1, vs = blockIdx.x & 1;
    const int tid = threadIdx.x, lane = tid & 63, wave = tid >> 6;
    const int l15 = lane & 15, quad = lane >> 4;
    const int vrow = wave * 16 + l15;

    __shared__ __align__(16) _Float16 Sh[8192];
    __shared__ __align__(16) _Float16 Dt[4096];
    __shared__ __align__(16) _Float16 LUg[8704];
    __shared__ __align__(16) _Float16 LWt[4608];
    __shared__ __align__(16) _Float16 LKh[9216];
    __shared__ __align__(16) _Float16 LQg[8704];
    __shared__ __align__(16) _Float16 LLg[4608];

    floatx4 Sacc[8];
#pragma unroll
    for (int kt = 0; kt < 8; ++kt) Sacc[kt] = 0;
    for (int i = tid; i < 1024; i += 256) *(int4*)&Sh[i * 8] = make_int4(0, 0, 0, 0);
    __syncthreads();

    for (int c = 0; c < 16; ++c) {
        const _Float16* CHb = CH + (size_t)(c * 16 + h) * 36864;
        {
            const int4* src = (const int4*)CHb;
#pragma unroll
            for (int i = 0; i < 4; ++i) {
                const int idx = tid + i * 256;
                *(int4*)&LUg[((idx >> 4) * 17 + (idx & 15)) * 8] = src[idx];
            }
        }
        {
            const int4* src = (const int4*)(CHb + 8192 + vs * 4096);
#pragma unroll
            for (int i = 0; i < 2; ++i) {
                const int idx = tid + i * 256;
                *(int4*)&LWt[((idx >> 3) * 9 + (idx & 7)) * 8] = src[idx];
            }
        }
        {
            const int4* src = (const int4*)(CHb + 16384);
#pragma unroll
            for (int i = 0; i < 4; ++i) {
                const int idx = tid + i * 256;
                *(int4*)&LKh[((idx >> 3) * 9 + (idx & 7)) * 8] = src[idx];
            }
        }
        {
            const int4* src = (const int4*)(CHb + 24576);
#pragma unroll
            for (int i = 0; i < 4; ++i) {
                const int idx = tid + i * 256;
                *(int4*)&LQg[((idx >> 4) * 17 + (idx & 15)) * 8] = src[idx];
            }
        }
        {
            const int4* src = (const int4*)(CHb + 32768);
#pragma unroll
            for (int i = 0; i < 2; ++i) {
                const int idx = tid + i * 256;
                *(int4*)&LLg[((idx >> 3) * 9 + (idx & 7)) * 8] = src[idx];
            }
        }
        __syncthreads();

        half8 bs[4];
#pragma unroll
        for (int ks = 0; ks < 4; ++ks) {
            const int kc = ks * 4 + quad;
            bs[ks] = *(const half8*)&Sh[(vrow * 16 + (kc ^ (vrow & 15))) * 8];
        }
#pragma unroll
        for (int ct = 0; ct < 4; ++ct) {
            floatx4 xa = {0.f, 0.f, 0.f, 0.f};
#pragma unroll
            for (int ks = 0; ks < 4; ++ks) {
                half8 af = *(const half8*)&LUg[((ct * 16 + l15) * 17 + ks * 4 + quad) * 8];
                xa = __builtin_amdgcn_mfma_f32_16x16x32_f16(af, bs[ks], xa, 0, 0, 0);
            }
            half4 w4 = *(const half4*)&LWt[(vrow * 9 + ct * 2 + (quad >> 1)) * 8 + (quad & 1) * 4];
            half4 d4;
#pragma unroll
            for (int r = 0; r < 4; ++r) d4[r] = (_Float16)((float)w4[r] - xa[r]);
            const int cc = ct * 2 + (quad >> 1);
            *(half4*)&Dt[(vrow * 8 + (cc ^ (vrow & 7))) * 8 + (quad & 1) * 4] = d4;
        }
        half8 bd[2];
#pragma unroll
        for (int cs = 0; cs < 2; ++cs) {
            const int cc = cs * 4 + quad;
            bd[cs] = *(const half8*)&Dt[(vrow * 8 + (cc ^ (vrow & 7))) * 8];
        }
#pragma unroll
        for (int ct = 0; ct < 4; ++ct) {
            floatx4 oa = {0.f, 0.f, 0.f, 0.f};
#pragma unroll
            for (int ks = 0; ks < 4; ++ks) {
                half8 af = *(const half8*)&LQg[((ct * 16 + l15) * 17 + ks * 4 + quad) * 8];
                oa = __builtin_amdgcn_mfma_f32_16x16x32_f16(af, bs[ks], oa, 0, 0, 0);
            }
#pragma unroll
            for (int cs = 0; cs < 2; ++cs) {
                half8 af = *(const half8*)&LLg[((ct * 16 + l15) * 9 + cs * 4 + quad) * 8];
                oa = __builtin_amdgcn_mfma_f32_16x16x32_f16(af, bd[cs], oa, 0, 0, 0);
            }
            const int tg = c * 64 + ct * 16 + quad * 4;
            const int col = h * 128 + vs * 64 + vrow;
#pragma unroll
            for (int r = 0; r < 4; ++r) o[(size_t)(tg + r) * 2048 + col] = oa[r];
        }
        const float gC = gamC[c * 16 + h];
#pragma unroll
        for (int kt = 0; kt < 8; ++kt) {
#pragma unroll
            for (int r = 0; r < 4; ++r) Sacc[kt][r] *= gC;
#pragma unroll
            for (int cs = 0; cs < 2; ++cs) {
                half8 af = *(const half8*)&LKh[((kt * 16 + l15) * 9 + cs * 4 + quad) * 8];
                Sacc[kt] = __builtin_amdgcn_mfma_f32_16x16x32_f16(af, bd[cs], Sacc[kt], 0, 0, 0);
            }
        }
#pragma unroll
        for (int kt = 0; kt < 8; ++kt) {
            const int kc = kt * 2 + (quad >> 1);
            half4 s4;
#pragma unroll
            for (int r = 0; r < 4; ++r) s4[r] = (_Float16)Sacc[kt][r];
            *(half4*)&Sh[(vrow * 16 + (kc ^ (vrow & 15))) * 8 + (quad & 1) * 4] = s4;
        }
        __syncthreads();
    }
}

// ---------------------------------------------------------------------------
// Gated RMSNorm: xf = o * silu(z); xn = xf * rsqrt(mean(xf^2)+eps) * w
// ---------------------------------------------------------------------------
__global__ __launch_bounds__(64) void gated_norm(const float* __restrict__ o,
                                                 const _Float16* __restrict__ qkvz,
                                                 const float* __restrict__ nw,
                                                 _Float16* __restrict__ xn) {
    const int b = blockIdx.x;
    const int t = b >> 4;
    const int vh = b & 15;
    const int kh = vh >> 1;
    const int r = vh & 1;
    const float* op = o + (size_t)t * 2048 + vh * 128;
    const _Float16* zp = qkvz + (size_t)t * QKVZ_N + kh * 768 + 512 + r * 128;
    const int j = threadIdx.x * 2;
    const float2 ov = *(const float2*)(op + j);
    const half2t zv = *(const half2t*)(zp + j);
    const float z0 = (float)zv[0], z1 = (float)zv[1];
    const float f0 = ov.x * z0 / (1.f + expf(-z0));
    const float f1 = ov.y * z1 / (1.f + expf(-z1));
    float ss = f0 * f0 + f1 * f1;
#pragma unroll
    for (int m = 1; m < 64; m <<= 1) ss += __shfl_xor(ss, m, 64);
    const float rs = rsqrtf(ss * (1.f / 128.f) + 1e-6f);
    _Float16* xp = xn + (size_t)t * 2048 + vh * 128;
    half2t y;
    y[0] = (_Float16)(f0 * rs * nw[j]);
    y[1] = (_Float16)(f1 * rs * nw[j + 1]);
    *(half2t*)(xp + j) = y;
}

// ---------------------------------------------------------------------------
extern "C" void kernel_launch(void* const* d_in, const int* in_sizes, int n_in,
                              void* d_out, int out_size, void* d_ws, size_t ws_size,
                              hipStream_t stream) {
    const float* hidden  = (const float*)d_in[0];
    const float* w_qkvz  = (const float*)d_in[1];
    const float* w_ba    = (const float*)d_in[2];
    const float* conv_w  = (const float*)d_in[3];
    const float* dt_bias = (const float*)d_in[4];
    const float* A_log   = (const float*)d_in[5];
    const float* norm_w  = (const float*)d_in[6];
    const float* w_out   = (const float*)d_in[7];
    float* out = (float*)d_out;

    // workspace layout (~63.2 MB), lifetime-based overlaps:
    //   hidden_h overlaps o        (hidden_h dead after qkvz GEMM)
    //   CH + xn_h overlap wqkvz_h  (wqkvz_h dead after qkvz GEMM)
    char* w = (char*)d_ws;
    _Float16*  qkvz_h = (_Float16*)(w);                 // 12,582,912 B (fp16)
    _Float16*  qch    = (_Float16*)(w + 12713984);      //  2,097,152 B
    _Float16*  kch    = (_Float16*)(w + 14811136);      //  2,097,152 B
    _Float16*  vch    = (_Float16*)(w + 16908288);      //  4,194,304 B
    float*     lgd    = (float*)(w + 21102592);         //     65,536 B
    float*     bet    = (float*)(w + 21168128);         //     65,536 B
    float*     gamC   = (float*)(w + 21233664);         //      4,096 B
    float*     o      = (float*)(w + 21237760);         //  8,388,608 B
    _Float16*  hid_h  = (_Float16*)(w + 21237760);      //  overlaps o
    _Float16*  wqk_h  = (_Float16*)(w + 29626368);      // 25,165,824 B
    _Float16*  CH     = (_Float16*)(w + 29626368);      //  overlaps wqk_h
    _Float16*  xn_h   = (_Float16*)(w + 29626368 + 18874368);  // after CH
    _Float16*  wout_h = (_Float16*)(w + 54792192);      //  8,388,608 B

    const int n0 = HIDDEN * T_LEN / 4;       //  524,288 float4s
    const int n1 = QKVZ_N * HIDDEN / 4;      // 3,145,728
    const int n2 = VAL_DIM * HIDDEN / 4;     // 1,048,576
    cvt3<<<(n0 + n1 + n2 + 255) / 256, 256, 0, stream>>>(hidden, hid_h, n0,
                                                         w_qkvz, wqk_h, n1,
                                                         w_out, wout_h, n2);

    gemm_h16<_Float16><<<8 * 48, 256, 0, stream>>>(hid_h, wqk_h, qkvz_h, 8, 48, HIDDEN);
    gemm_ba_gates<<<T_LEN, 256, 0, stream>>>(hidden, w_ba, dt_bias, A_log, lgd, bet);
    conv_silu<<<(T_LEN * 4096) / 256, 256, 0, stream>>>(qkvz_h, conv_w, qch, kch, vch);
    l2norm_qk<<<T_LEN * 16, 64, 0, stream>>>(qch, kch);
    chunk_prep<<<256, 256, 0, stream>>>(qch, kch, vch, lgd, bet, CH, gamC);
    chunk_scan<<<32, 256, 0, stream>>>(CH, gamC, o);
    gated_norm<<<T_LEN * 16, 64, 0, stream>>>(o, qkvz_h, norm_w, xn_h);
    gemm_h16<float><<<8 * 16, 256, 0, stream>>>(xn_h, wout_h, out, 8, 16, HIDDEN);
}